// Round 18
// baseline (245.781 us; speedup 1.0000x reference)
//
#include <hip/hip_runtime.h>
#include <math.h>

#define NB    200
#define DIMH  128
#define TPB8  512
#define ROWS8 8
#define NNEWT 6    // Newton iters on ||.||_10 (convex, monotone from tau_lo)
#define NITER 12   // minimal fallback kernel
#define NJT   13   // j-tiles of 16 covering 208
#define KJ2   112  // padded j-pairs for PV (224 j's)
#define PBLK  (2 * ROWS8 * 116)   // p-frag u32 per block (hi+lo)

typedef __attribute__((ext_vector_type(8))) short  short8v;
typedef __attribute__((ext_vector_type(4))) float  f32x4;
typedef __attribute__((ext_vector_type(4))) unsigned u32x4;

#define WF_U32 32768   // W-frag table: 8nt*8ks*64lane*4 u32 (hi) + same (lo)

__device__ __forceinline__ unsigned pack_hi2(float a, float b){
    return (__builtin_bit_cast(unsigned, a) >> 16) |
           (__builtin_bit_cast(unsigned, b) & 0xFFFF0000u);
}
__device__ __forceinline__ float hi_of(float x){
    return __builtin_bit_cast(float, __builtin_bit_cast(unsigned, x) & 0xFFFF0000u);
}
__device__ __forceinline__ float rdlane(float v, int l){
    return __builtin_bit_cast(float,
        __builtin_amdgcn_readlane(__builtin_bit_cast(int, v), l));
}
__device__ __forceinline__ float wsum_dpp(float v){
#define DPP_ADD(ctrl, rmask)                                                     \
    {                                                                            \
        int t_ = __builtin_amdgcn_update_dpp(0, __builtin_bit_cast(int, v),      \
                                             ctrl, rmask, 0xf, false);           \
        v += __builtin_bit_cast(float, t_);                                      \
    }
    DPP_ADD(0x111, 0xf)
    DPP_ADD(0x112, 0xf)
    DPP_ADD(0x114, 0xf)
    DPP_ADD(0x118, 0xf)
    DPP_ADD(0x142, 0xa)
    DPP_ADD(0x143, 0xc)
#undef DPP_ADD
    return rdlane(v, 63);
}
__device__ __forceinline__ void wsum2_dpp(float& a, float& b){
#define DPP2(ctrl, rmask)                                                        \
    {                                                                            \
        int ta = __builtin_amdgcn_update_dpp(0, __builtin_bit_cast(int, a),      \
                                             ctrl, rmask, 0xf, false);           \
        int tb = __builtin_amdgcn_update_dpp(0, __builtin_bit_cast(int, b),      \
                                             ctrl, rmask, 0xf, false);           \
        a += __builtin_bit_cast(float, ta);                                      \
        b += __builtin_bit_cast(float, tb);                                      \
    }
    DPP2(0x111, 0xf)
    DPP2(0x112, 0xf)
    DPP2(0x114, 0xf)
    DPP2(0x118, 0xf)
    DPP2(0x142, 0xa)
    DPP2(0x143, 0xc)
#undef DPP2
    a = rdlane(a, 63);
    b = rdlane(b, 63);
}
__device__ __forceinline__ float wmax_dpp(float v){
#define DPP_MAX(ctrl, rmask)                                                     \
    {                                                                            \
        int t_ = __builtin_amdgcn_update_dpp(__builtin_bit_cast(int, v),         \
                                             __builtin_bit_cast(int, v),         \
                                             ctrl, rmask, 0xf, false);           \
        v = fmaxf(v, __builtin_bit_cast(float, t_));                             \
    }
    DPP_MAX(0x111, 0xf)
    DPP_MAX(0x112, 0xf)
    DPP_MAX(0x114, 0xf)
    DPP_MAX(0x118, 0xf)
    DPP_MAX(0x142, 0xa)
    DPP_MAX(0x143, 0xc)
#undef DPP_MAX
    return rdlane(v, 63);
}

// One-time W -> bf16 hi/lo fragment table (gate MFMA B layout). Validated r10/r11.
__global__ __launch_bounds__(64) void conv_w(const float* __restrict__ W,
                                             unsigned* __restrict__ wf){
    const int lane = threadIdx.x;
    const int ks = blockIdx.x & 7, nt = blockIdx.x >> 3;
    const int krow = ks * 32 + (lane >> 4) * 8;
    const int col  = nt * 16 + (lane & 15);
    unsigned hi[4], lo[4];
    #pragma unroll
    for (int q2 = 0; q2 < 4; ++q2) {
        float v0 = W[(size_t)(krow + 2 * q2) * DIMH + col];
        float v1 = W[(size_t)(krow + 2 * q2 + 1) * DIMH + col];
        hi[q2] = pack_hi2(v0, v1);
        lo[q2] = pack_hi2(v0 - hi_of(v0), v1 - hi_of(v1));
    }
    const unsigned base = (blockIdx.x * 64 + lane) * 4;
    *(u32x4*)&wf[base]              = (u32x4){hi[0], hi[1], hi[2], hi[3]};
    *(u32x4*)&wf[WF_U32 / 2 + base] = (u32x4){lo[0], lo[1], lo[2], lo[3]};
}

// hidden -> hs[b][j][d2] bf16 hi/lo (score B layout). Validated r11.
__global__ __launch_bounds__(256) void conv_hs(const float* __restrict__ hidden,
                                               unsigned* __restrict__ hs_hi,
                                               unsigned* __restrict__ hs_lo){
    size_t gid = (size_t)blockIdx.x * 256 + threadIdx.x;
    float2 h2 = *(const float2*)(hidden + gid * 2);
    hs_hi[gid] = pack_hi2(h2.x, h2.y);
    hs_lo[gid] = pack_hi2(h2.x - hi_of(h2.x), h2.y - hi_of(h2.y));
}

// hidden -> ht[b][d][j2] bf16 (transposed, padded to 224 j: PV B layout, hi only).
__global__ __launch_bounds__(256) void conv_ht(const float* __restrict__ hidden,
                                               unsigned* __restrict__ ht_hi){
    __shared__ float tile[32][33];
    const int bid = blockIdx.x;
    const int b  = bid / 28;
    const int rem = bid % 28;
    const int jt = rem >> 2, dt = rem & 3;
    const int j0 = jt * 32, d0 = dt * 32;
    const int tt = threadIdx.x;
    #pragma unroll
    for (int rr = 0; rr < 4; ++rr) {
        int j = j0 + (tt >> 5) + rr * 8;
        int d = d0 + (tt & 31);
        tile[(tt >> 5) + rr * 8][tt & 31] =
            (j < NB) ? hidden[((size_t)b * NB + j) * DIMH + d] : 0.0f;
    }
    __syncthreads();
    #pragma unroll
    for (int it = 0; it < 2; ++it) {
        int j2 = it * 8 + (tt & 7);
        int dl = tt >> 3;
        float v0 = tile[2 * j2][dl];
        float v1 = tile[2 * j2 + 1][dl];
        size_t o = ((size_t)b * DIMH + d0 + dl) * KJ2 + (j0 >> 1) + j2;
        ht_hi[o] = pack_hi2(v0, v1);
    }
}

// ========== r18 kernel 1: score + entmax -> p fragments in ws ==========
// Homogeneous short-chain kernel: 2 barriers, retires after entmax.
__global__ __launch_bounds__(TPB8, 4) void la_score(
    const float* __restrict__ hidden,
    const int*   __restrict__ adj,
    const int*   __restrict__ mask,
    const float* __restrict__ a0, const float* __restrict__ a1,
    const float* __restrict__ a2, const float* __restrict__ a3,
    const unsigned* __restrict__ hs_hi, const unsigned* __restrict__ hs_lo,
    unsigned* __restrict__ pws)
{
    __shared__ __align__(16) unsigned hab[2][32][68];
    __shared__ float xs[ROWS8][208];

    const int t    = threadIdx.x;
    const int lane = t & 63;
    const int r    = t >> 6;
    // XCD swizzle (same mapping as la_pvgate -> same XCD reuses this block's p)
    const int bid  = (blockIdx.x & 7) * ((int)gridDim.x >> 3) + (blockIdx.x >> 3);
    const int b    = bid / (NB / ROWS8);
    const int i0   = (bid % (NB / ROWS8)) * ROWS8;

    const float* hb = hidden + (size_t)b * NB * DIMH;

    // ---- stage bf16 hi/lo ha table (coalesced) ----
    for (int s = t; s < 32 * 64; s += TPB8) {
        int rk = s >> 6, dd = s & 63;
        int rr = rk >> 2, k = rk & 3;
        int d  = dd * 2;
        const float* ap = (k == 0) ? a0 : (k == 1) ? a1 : (k == 2) ? a2 : a3;
        float h0 = hb[(i0 + rr) * DIMH + d];
        float h1 = hb[(i0 + rr) * DIMH + d + 1];
        float q0 = h0 * ap[d];
        float q1 = h1 * ap[d + 1];
        hab[0][rk][dd] = pack_hi2(q0, q1);
        hab[1][rk][dd] = pack_hi2(q0 - hi_of(q0), q1 - hi_of(q1));
    }
    __syncthreads();                                   // A

    short8v Ahi[2][4], Alo[2][4];
    {
        const int au = (lane >> 4) * 4;
        #pragma unroll
        for (int tl = 0; tl < 2; ++tl) {
            const int arow = tl * 16 + (lane & 15);
            #pragma unroll
            for (int ks = 0; ks < 4; ++ks) {
                Ahi[tl][ks] = __builtin_bit_cast(short8v, *(const u32x4*)&hab[0][arow][ks * 16 + au]);
                Alo[tl][ks] = __builtin_bit_cast(short8v, *(const u32x4*)&hab[1][arow][ks * 16 + au]);
            }
        }
    }

    const int jcol = lane & 15;
    const int kgrp = lane >> 4;
    for (int jt = r; jt < NJT; jt += 8) {
        const int jrow = jt * 16 + jcol;
        const int jl   = (jrow < NB) ? jrow : (NB - 1);
        f32x4 acc0 = {0.f, 0.f, 0.f, 0.f};
        f32x4 acc1 = {0.f, 0.f, 0.f, 0.f};
        const unsigned* bhp = hs_hi + ((size_t)(b * NB + jl) << 6) + kgrp * 4;
        const unsigned* blp = hs_lo + ((size_t)(b * NB + jl) << 6) + kgrp * 4;
        #pragma unroll
        for (int ks = 0; ks < 4; ++ks) {
            short8v Bh = __builtin_bit_cast(short8v, *(const u32x4*)(bhp + ks * 16));
            short8v Bl = __builtin_bit_cast(short8v, *(const u32x4*)(blp + ks * 16));
            acc0 = __builtin_amdgcn_mfma_f32_16x16x32_bf16(Ahi[0][ks], Bh, acc0, 0, 0, 0);
            acc0 = __builtin_amdgcn_mfma_f32_16x16x32_bf16(Alo[0][ks], Bh, acc0, 0, 0, 0);
            acc0 = __builtin_amdgcn_mfma_f32_16x16x32_bf16(Ahi[0][ks], Bl, acc0, 0, 0, 0);
            acc1 = __builtin_amdgcn_mfma_f32_16x16x32_bf16(Ahi[1][ks], Bh, acc1, 0, 0, 0);
            acc1 = __builtin_amdgcn_mfma_f32_16x16x32_bf16(Alo[1][ks], Bh, acc1, 0, 0, 0);
            acc1 = __builtin_amdgcn_mfma_f32_16x16x32_bf16(Ahi[1][ks], Bl, acc1, 0, 0, 0);
        }
        const int mm  = mask[b * NB + jl];
        const int kk0 = adj[(size_t)(b * NB + i0 + kgrp) * NB + jl];
        const int kk1 = adj[(size_t)(b * NB + i0 + 4 + kgrp) * NB + jl];
        float ev0 = (kk0 == 1) ? acc0[0] : (kk0 == 2) ? acc0[1] :
                    (kk0 == 3) ? acc0[2] : (kk0 == 4) ? acc0[3] : 0.0f;
        float ev1 = (kk1 == 1) ? acc1[0] : (kk1 == 2) ? acc1[1] :
                    (kk1 == 3) ? acc1[2] : (kk1 == 4) ? acc1[3] : 0.0f;
        ev0 = (ev0 >= 0.0f) ? ev0 : 0.2f * ev0;
        ev1 = (ev1 >= 0.0f) ? ev1 : 0.2f * ev1;
        float xv0 = ev0 * 0.1f;
        float xv1 = ev1 * 0.1f;
        if (mm == 0 || jrow >= NB) { xv0 = -INFINITY; xv1 = -INFINITY; }
        xs[kgrp][jrow]     = xv0;
        xs[4 + kgrp][jrow] = xv1;
    }
    __syncthreads();                                   // B

    // ---- entmax via Newton on ||(x-tau)+||_10 = 1 ----
    float x0 = xs[r][lane];
    float x1 = xs[r][lane + 64];
    float x2 = xs[r][lane + 128];
    float x3 = (lane < 16) ? xs[r][192 + lane] : -INFINITY;

    float mx  = wmax_dpp(fmaxf(fmaxf(x0, x1), fmaxf(x2, x3)));
    float tau = mx - 1.0f;
    #pragma unroll
    for (int itn = 0; itn < NNEWT; ++itn) {
        float t10 = 0.f, t9 = 0.f;
        #define ACC(xv) { float z_ = fmaxf((xv) - tau, 0.f); float e2 = z_*z_;   \
                          float e8 = e2*e2; e8 = e8*e8; float e9 = e8*z_;        \
                          t9 += e9; t10 = fmaf(e9, z_, t10); }
        ACC(x0) ACC(x1) ACC(x2) ACC(x3)
        #undef ACC
        wsum2_dpp(t10, t9);
        float u  = exp2f(0.1f * log2f(t10));
        tau += t10 * (1.0f - __builtin_amdgcn_rcpf(u)) * __builtin_amdgcn_rcpf(t9);
    }
    #define P10(v, tt) ({ float z_ = fmaxf((v) - (tt), 0.f); float z2 = z_*z_; float z4 = z2*z2; float z8 = z4*z4; z8*z2; })
    float p0 = P10(x0, tau);
    float p1 = P10(x1, tau);
    float p2 = P10(x2, tau);
    float p3 = P10(x3, tau);
    #undef P10
    float sinv = 1.0f / wsum_dpp(p0 + p1 + p2 + p3);
    xs[r][lane]       = p0 * sinv;                     // wave-local write-back
    xs[r][lane + 64]  = p1 * sinv;
    xs[r][lane + 128] = p2 * sinv;
    if (lane < 16) xs[r][192 + lane] = p3 * sinv;

    // ---- p fragments -> ws (wave-local xs reads; coalesced writes) ----
    unsigned* pb = pws + (size_t)bid * PBLK;
    for (int k2 = lane; k2 < KJ2; k2 += 64) {
        int j = 2 * k2;
        float v0 = (j < 208)     ? xs[r][j]     : 0.0f;
        float v1 = (j + 1 < 208) ? xs[r][j + 1] : 0.0f;
        pb[r * 116 + k2]               = pack_hi2(v0, v1);
        pb[ROWS8 * 116 + r * 116 + k2] = pack_hi2(v0 - hi_of(v0), v1 - hi_of(v1));
    }
}

// ========== r18 kernel 2: PV + gate (dense MFMA, 3 barriers) ==========
__global__ __launch_bounds__(TPB8, 4) void la_pvgate(
    const float* __restrict__ hidden,
    const float* __restrict__ bias,
    const unsigned* __restrict__ wf,
    const unsigned* __restrict__ ht_hi,
    const unsigned* __restrict__ pws,
    float* __restrict__ out)
{
    __shared__ float cop[ROWS8][256];          // [0:128)=h, [128:256)=o
    __shared__ __align__(16) unsigned cbf[2][ROWS8][132];
    __shared__ float gb[ROWS8][DIMH];

    const int t    = threadIdx.x;
    const int lane = t & 63;
    const int r    = t >> 6;
    const int d2   = 2 * lane;
    const int bid  = (blockIdx.x & 7) * ((int)gridDim.x >> 3) + (blockIdx.x >> 3);
    const int b    = bid / (NB / ROWS8);
    const int i0   = (bid % (NB / ROWS8)) * ROWS8;

    const float* hb = hidden + (size_t)b * NB * DIMH;

    // ---- stage h rows (barrier deferred to E) ----
    for (int idx = t; idx < ROWS8 * DIMH; idx += TPB8) {
        int rr = idx >> 7, d = idx & 127;
        cop[rr][d] = hb[(i0 + rr) * DIMH + d];
    }

    // ---- PV via MFMA: wave r does n-tile r; p frags straight from ws ----
    {
        const unsigned* pb = pws + (size_t)bid * PBLK;
        f32x4 av = {0.f, 0.f, 0.f, 0.f};
        const int prow = lane & 7;
        const int au   = (lane >> 4) * 4;
        const int dc   = 16 * r + (lane & 15);
        const size_t base = ((size_t)(b * DIMH + dc)) * KJ2 + au;
        #pragma unroll
        for (int ks = 0; ks < 7; ++ks) {
            short8v Ph = __builtin_bit_cast(short8v, *(const u32x4*)(pb + prow * 116 + ks * 16 + au));
            short8v Pl = __builtin_bit_cast(short8v, *(const u32x4*)(pb + ROWS8 * 116 + prow * 116 + ks * 16 + au));
            short8v Bh = __builtin_bit_cast(short8v, *(const u32x4*)(ht_hi + base + ks * 16));
            av = __builtin_amdgcn_mfma_f32_16x16x32_bf16(Ph, Bh, av, 0, 0, 0);
            av = __builtin_amdgcn_mfma_f32_16x16x32_bf16(Pl, Bh, av, 0, 0, 0);
        }
        if (lane < 32) {
            const int rbase = (lane >> 4) * 4;
            #pragma unroll
            for (int q = 0; q < 4; ++q)
                cop[rbase + q][DIMH + 16 * r + (lane & 15)] = av[q];
        }
    }
    __syncthreads();                                   // E: h staged + o complete

    float2 ovv = *(const float2*)&cop[r][DIMH + d2];

    // ---- gate: C hi/lo x W bf16; wave r does n-tile r ----
    {
        float hx = cop[r][d2], hy = cop[r][d2 + 1];
        cbf[0][r][lane]      = pack_hi2(hx, hy);
        cbf[1][r][lane]      = pack_hi2(hx - hi_of(hx), hy - hi_of(hy));
        cbf[0][r][64 + lane] = pack_hi2(ovv.x, ovv.y);
        cbf[1][r][64 + lane] = pack_hi2(ovv.x - hi_of(ovv.x), ovv.y - hi_of(ovv.y));
    }
    __syncthreads();                                   // F

    {
        f32x4 ga = {0.f, 0.f, 0.f, 0.f};
        const int arow = lane & 7;
        const int au   = (lane >> 4) * 4;
        #pragma unroll
        for (int ks = 0; ks < 8; ++ks) {
            short8v Ah = __builtin_bit_cast(short8v, *(const u32x4*)&cbf[0][arow][ks * 16 + au]);
            short8v Al = __builtin_bit_cast(short8v, *(const u32x4*)&cbf[1][arow][ks * 16 + au]);
            const unsigned bi = ((r * 8 + ks) * 64 + lane) * 4;
            short8v Bh = __builtin_bit_cast(short8v, *(const u32x4*)&wf[bi]);
            ga = __builtin_amdgcn_mfma_f32_16x16x32_bf16(Ah, Bh, ga, 0, 0, 0);
            ga = __builtin_amdgcn_mfma_f32_16x16x32_bf16(Al, Bh, ga, 0, 0, 0);
        }
        if (lane < 32) {
            const int rbase = (lane >> 4) * 4;
            #pragma unroll
            for (int q = 0; q < 4; ++q)
                gb[rbase + q][16 * r + (lane & 15)] = ga[q];
        }
    }
    __syncthreads();                                   // G

    // ---- final ----
    {
        float2 bv = *(const float2*)(bias + d2);
        float gx = gb[r][d2]     + bv.x;
        float gy = gb[r][d2 + 1] + bv.y;
        float sgx = 1.0f / (1.0f + __expf(-gx));
        float sgy = 1.0f / (1.0f + __expf(-gy));
        float2 hf = *(const float2*)&cop[r][d2];
        const size_t gi = (size_t)(b * NB + i0 + r) * DIMH;
        float2 res;
        res.x = sgx * ovv.x + (1.0f - sgx) * hf.x;
        res.y = sgy * ovv.y + (1.0f - sgy) * hf.y;
        *(float2*)(out + gi + d2) = res;
    }
}

// ========== fallback A: r17 fused 8-row kernel (ws fits tables, not p) ==========
__global__ __launch_bounds__(TPB8, 4) void la_fused8(
    const float* __restrict__ hidden,
    const int*   __restrict__ adj,
    const int*   __restrict__ mask,
    const float* __restrict__ a0, const float* __restrict__ a1,
    const float* __restrict__ a2, const float* __restrict__ a3,
    const float* __restrict__ bias,
    const unsigned* __restrict__ wf,
    const unsigned* __restrict__ hs_hi, const unsigned* __restrict__ hs_lo,
    const unsigned* __restrict__ ht_hi,
    float* __restrict__ out)
{
    __shared__ __align__(16) unsigned hab[2][32][68];
    __shared__ float xs[ROWS8][208];
    __shared__ float cop[ROWS8][256];
    __shared__ __align__(16) unsigned ucb[2 * ROWS8 * 132];

    unsigned* pbf = ucb;
    #define CBF(part, row, idx) ucb[(part) * (ROWS8 * 132) + (row) * 132 + (idx)]

    const int t    = threadIdx.x;
    const int lane = t & 63;
    const int r    = t >> 6;
    const int d2   = 2 * lane;
    const int bid  = (blockIdx.x & 7) * ((int)gridDim.x >> 3) + (blockIdx.x >> 3);
    const int b    = bid / (NB / ROWS8);
    const int i0   = (bid % (NB / ROWS8)) * ROWS8;

    const float* hb = hidden + (size_t)b * NB * DIMH;

    for (int idx = t; idx < ROWS8 * DIMH; idx += TPB8) {
        int rr = idx >> 7, d = idx & 127;
        cop[rr][d] = hb[(i0 + rr) * DIMH + d];
    }
    for (int s = t; s < 32 * 64; s += TPB8) {
        int rk = s >> 6, dd = s & 63;
        int rr = rk >> 2, k = rk & 3;
        int d  = dd * 2;
        const float* ap = (k == 0) ? a0 : (k == 1) ? a1 : (k == 2) ? a2 : a3;
        float h0 = hb[(i0 + rr) * DIMH + d];
        float h1 = hb[(i0 + rr) * DIMH + d + 1];
        float q0 = h0 * ap[d];
        float q1 = h1 * ap[d + 1];
        hab[0][rk][dd] = pack_hi2(q0, q1);
        hab[1][rk][dd] = pack_hi2(q0 - hi_of(q0), q1 - hi_of(q1));
    }
    __syncthreads();

    short8v Ahi[2][4], Alo[2][4];
    {
        const int au = (lane >> 4) * 4;
        #pragma unroll
        for (int tl = 0; tl < 2; ++tl) {
            const int arow = tl * 16 + (lane & 15);
            #pragma unroll
            for (int ks = 0; ks < 4; ++ks) {
                Ahi[tl][ks] = __builtin_bit_cast(short8v, *(const u32x4*)&hab[0][arow][ks * 16 + au]);
                Alo[tl][ks] = __builtin_bit_cast(short8v, *(const u32x4*)&hab[1][arow][ks * 16 + au]);
            }
        }
    }

    const int jcol = lane & 15;
    const int kgrp = lane >> 4;
    for (int jt = r; jt < NJT; jt += 8) {
        const int jrow = jt * 16 + jcol;
        const int jl   = (jrow < NB) ? jrow : (NB - 1);
        f32x4 acc0 = {0.f, 0.f, 0.f, 0.f};
        f32x4 acc1 = {0.f, 0.f, 0.f, 0.f};
        const unsigned* bhp = hs_hi + ((size_t)(b * NB + jl) << 6) + kgrp * 4;
        const unsigned* blp = hs_lo + ((size_t)(b * NB + jl) << 6) + kgrp * 4;
        #pragma unroll
        for (int ks = 0; ks < 4; ++ks) {
            short8v Bh = __builtin_bit_cast(short8v, *(const u32x4*)(bhp + ks * 16));
            short8v Bl = __builtin_bit_cast(short8v, *(const u32x4*)(blp + ks * 16));
            acc0 = __builtin_amdgcn_mfma_f32_16x16x32_bf16(Ahi[0][ks], Bh, acc0, 0, 0, 0);
            acc0 = __builtin_amdgcn_mfma_f32_16x16x32_bf16(Alo[0][ks], Bh, acc0, 0, 0, 0);
            acc0 = __builtin_amdgcn_mfma_f32_16x16x32_bf16(Ahi[0][ks], Bl, acc0, 0, 0, 0);
            acc1 = __builtin_amdgcn_mfma_f32_16x16x32_bf16(Ahi[1][ks], Bh, acc1, 0, 0, 0);
            acc1 = __builtin_amdgcn_mfma_f32_16x16x32_bf16(Alo[1][ks], Bh, acc1, 0, 0, 0);
            acc1 = __builtin_amdgcn_mfma_f32_16x16x32_bf16(Ahi[1][ks], Bl, acc1, 0, 0, 0);
        }
        const int mm  = mask[b * NB + jl];
        const int kk0 = adj[(size_t)(b * NB + i0 + kgrp) * NB + jl];
        const int kk1 = adj[(size_t)(b * NB + i0 + 4 + kgrp) * NB + jl];
        float ev0 = (kk0 == 1) ? acc0[0] : (kk0 == 2) ? acc0[1] :
                    (kk0 == 3) ? acc0[2] : (kk0 == 4) ? acc0[3] : 0.0f;
        float ev1 = (kk1 == 1) ? acc1[0] : (kk1 == 2) ? acc1[1] :
                    (kk1 == 3) ? acc1[2] : (kk1 == 4) ? acc1[3] : 0.0f;
        ev0 = (ev0 >= 0.0f) ? ev0 : 0.2f * ev0;
        ev1 = (ev1 >= 0.0f) ? ev1 : 0.2f * ev1;
        float xv0 = ev0 * 0.1f;
        float xv1 = ev1 * 0.1f;
        if (mm == 0 || jrow >= NB) { xv0 = -INFINITY; xv1 = -INFINITY; }
        xs[kgrp][jrow]     = xv0;
        xs[4 + kgrp][jrow] = xv1;
    }
    __syncthreads();

    float x0 = xs[r][lane];
    float x1 = xs[r][lane + 64];
    float x2 = xs[r][lane + 128];
    float x3 = (lane < 16) ? xs[r][192 + lane] : -INFINITY;

    float mx  = wmax_dpp(fmaxf(fmaxf(x0, x1), fmaxf(x2, x3)));
    float tau = mx - 1.0f;
    #pragma unroll
    for (int itn = 0; itn < NNEWT; ++itn) {
        float t10 = 0.f, t9 = 0.f;
        #define ACC(xv) { float z_ = fmaxf((xv) - tau, 0.f); float e2 = z_*z_;   \
                          float e8 = e2*e2; e8 = e8*e8; float e9 = e8*z_;        \
                          t9 += e9; t10 = fmaf(e9, z_, t10); }
        ACC(x0) ACC(x1) ACC(x2) ACC(x3)
        #undef ACC
        wsum2_dpp(t10, t9);
        float u  = exp2f(0.1f * log2f(t10));
        tau += t10 * (1.0f - __builtin_amdgcn_rcpf(u)) * __builtin_amdgcn_rcpf(t9);
    }
    #define P10(v, tt) ({ float z_ = fmaxf((v) - (tt), 0.f); float z2 = z_*z_; float z4 = z2*z2; float z8 = z4*z4; z8*z2; })
    float p0 = P10(x0, tau);
    float p1 = P10(x1, tau);
    float p2 = P10(x2, tau);
    float p3 = P10(x3, tau);
    #undef P10
    float sinv = 1.0f / wsum_dpp(p0 + p1 + p2 + p3);
    xs[r][lane]       = p0 * sinv;
    xs[r][lane + 64]  = p1 * sinv;
    xs[r][lane + 128] = p2 * sinv;
    if (lane < 16) xs[r][192 + lane] = p3 * sinv;

    for (int k2 = lane; k2 < KJ2; k2 += 64) {
        int j = 2 * k2;
        float v0 = (j < 208)     ? xs[r][j]     : 0.0f;
        float v1 = (j + 1 < 208) ? xs[r][j + 1] : 0.0f;
        pbf[r * 116 + k2]                = pack_hi2(v0, v1);
        pbf[ROWS8 * 116 + r * 116 + k2]  = pack_hi2(v0 - hi_of(v0), v1 - hi_of(v1));
    }
    __syncthreads();

    {
        f32x4 av = {0.f, 0.f, 0.f, 0.f};
        const int prow = lane & 7;
        const int au   = (lane >> 4) * 4;
        const int dc   = 16 * r + (lane & 15);
        const size_t base = ((size_t)(b * DIMH + dc)) * KJ2 + au;
        #pragma unroll
        for (int ks = 0; ks < 7; ++ks) {
            short8v Ph = __builtin_bit_cast(short8v, *(const u32x4*)&pbf[prow * 116 + ks * 16 + au]);
            short8v Pl = __builtin_bit_cast(short8v, *(const u32x4*)&pbf[ROWS8 * 116 + prow * 116 + ks * 16 + au]);
            short8v Bh = __builtin_bit_cast(short8v, *(const u32x4*)(ht_hi + base + ks * 16));
            av = __builtin_amdgcn_mfma_f32_16x16x32_bf16(Ph, Bh, av, 0, 0, 0);
            av = __builtin_amdgcn_mfma_f32_16x16x32_bf16(Pl, Bh, av, 0, 0, 0);
        }
        if (lane < 32) {
            const int rbase = (lane >> 4) * 4;
            #pragma unroll
            for (int q = 0; q < 4; ++q)
                cop[rbase + q][DIMH + 16 * r + (lane & 15)] = av[q];
        }
    }
    __syncthreads();

    float2 ovv = *(const float2*)&cop[r][DIMH + d2];

    {
        float hx = cop[r][d2], hy = cop[r][d2 + 1];
        CBF(0, r, lane)      = pack_hi2(hx, hy);
        CBF(1, r, lane)      = pack_hi2(hx - hi_of(hx), hy - hi_of(hy));
        CBF(0, r, 64 + lane) = pack_hi2(ovv.x, ovv.y);
        CBF(1, r, 64 + lane) = pack_hi2(ovv.x - hi_of(ovv.x), ovv.y - hi_of(ovv.y));
    }
    __syncthreads();

    {
        f32x4 ga = {0.f, 0.f, 0.f, 0.f};
        const int arow = lane & 7;
        const int au   = (lane >> 4) * 4;
        #pragma unroll
        for (int ks = 0; ks < 8; ++ks) {
            short8v Ah = __builtin_bit_cast(short8v, *(const u32x4*)&CBF(0, arow, ks * 16 + au));
            short8v Al = __builtin_bit_cast(short8v, *(const u32x4*)&CBF(1, arow, ks * 16 + au));
            const unsigned bi = ((r * 8 + ks) * 64 + lane) * 4;
            short8v Bh = __builtin_bit_cast(short8v, *(const u32x4*)&wf[bi]);
            ga = __builtin_amdgcn_mfma_f32_16x16x32_bf16(Ah, Bh, ga, 0, 0, 0);
            ga = __builtin_amdgcn_mfma_f32_16x16x32_bf16(Al, Bh, ga, 0, 0, 0);
        }
        if (lane < 32) {
            const int rbase = (lane >> 4) * 4;
            #pragma unroll
            for (int q = 0; q < 4; ++q)
                xs[rbase + q][16 * r + (lane & 15)] = ga[q];
        }
    }
    __syncthreads();

    {
        float2 bv = *(const float2*)(bias + d2);
        float gx = xs[r][d2]     + bv.x;
        float gy = xs[r][d2 + 1] + bv.y;
        float sgx = 1.0f / (1.0f + __expf(-gx));
        float sgy = 1.0f / (1.0f + __expf(-gy));
        float2 hf = *(const float2*)&cop[r][d2];
        const size_t gi = (size_t)(b * NB + i0 + r) * DIMH;
        float2 res;
        res.x = sgx * ovv.x + (1.0f - sgx) * hf.x;
        res.y = sgy * ovv.y + (1.0f - sgy) * hf.y;
        *(float2*)(out + gi + d2) = res;
    }
    #undef CBF
}

// ========== fallback B: no-ws 4-row f32 kernel (round-9 structure) ==========
#define ROWS  4
#define TPB   256
__global__ __launch_bounds__(TPB, 4) void la_basic(
    const float* __restrict__ hidden,
    const int*   __restrict__ adj,
    const int*   __restrict__ mask,
    const float* __restrict__ a0, const float* __restrict__ a1,
    const float* __restrict__ a2, const float* __restrict__ a3,
    const float* __restrict__ W,  const float* __restrict__ bias,
    float* __restrict__ out)
{
    __shared__ float ha[ROWS][4][132];
    __shared__ float xs[ROWS][208];
    __shared__ float cop[ROWS][256];
    __shared__ float scrf[ROWS * ROWS * DIMH];

    const int t    = threadIdx.x;
    const int lane = t & 63;
    const int r    = t >> 6;
    const int d2   = 2 * lane;
    const int bid  = blockIdx.x;
    const int b    = bid / (NB / ROWS);
    const int i0   = (bid % (NB / ROWS)) * ROWS;

    const float* hb = hidden + (size_t)b * NB * DIMH;

    for (int idx = t; idx < ROWS * DIMH; idx += TPB) {
        int rr = idx >> 7, d = idx & 127;
        cop[rr][d] = hb[(i0 + rr) * DIMH + d];
    }
    for (int idx = t; idx < ROWS * 4 * DIMH; idx += TPB) {
        int rr = idx >> 9, k = (idx >> 7) & 3, d = idx & 127;
        float av = (k == 0) ? a0[d] : (k == 1) ? a1[d] : (k == 2) ? a2[d] : a3[d];
        ha[rr][k][d] = hb[(i0 + rr) * DIMH + d] * av;
    }
    __syncthreads();

    if (t < NB) {
        const int m = mask[b * NB + t];
        int kk[ROWS];
        #pragma unroll
        for (int rr = 0; rr < ROWS; rr++)
            kk[rr] = adj[((size_t)(b * NB + i0 + rr)) * NB + t];
        int ksel[ROWS];
        #pragma unroll
        for (int rr = 0; rr < ROWS; rr++) ksel[rr] = (kk[rr] > 0) ? (kk[rr] - 1) : 0;
        float acc[ROWS] = {0.f, 0.f, 0.f, 0.f};
        const float* hj = hb + t * DIMH;
        #pragma unroll 4
        for (int d = 0; d < DIMH; d += 4) {
            float4 hv = *(const float4*)(hj + d);
            #pragma unroll
            for (int rr = 0; rr < ROWS; rr++) {
                const float4 av4 = *(const float4*)&ha[rr][ksel[rr]][d];
                acc[rr] = fmaf(hv.x, av4.x, acc[rr]);
                acc[rr] = fmaf(hv.y, av4.y, acc[rr]);
                acc[rr] = fmaf(hv.z, av4.z, acc[rr]);
                acc[rr] = fmaf(hv.w, av4.w, acc[rr]);
            }
        }
        #pragma unroll
        for (int rr = 0; rr < ROWS; rr++) {
            float x;
            if (m == 0)           x = -INFINITY;
            else if (kk[rr] == 0) x = 0.0f;
            else {
                float e = acc[rr];
                e = (e >= 0.0f) ? e : 0.2f * e;
                x = e * 0.1f;
            }
            xs[rr][t] = x;
        }
    } else if (t < 208) {
        #pragma unroll
        for (int rr = 0; rr < ROWS; rr++) xs[rr][t] = -INFINITY;
    }
    __syncthreads();

    float x0 = xs[r][lane];
    float x1 = xs[r][lane + 64];
    float x2 = xs[r][lane + 128];
    float x3 = (lane < 16) ? xs[r][192 + lane] : -INFINITY;

    float mx  = wmax_dpp(fmaxf(fmaxf(x0, x1), fmaxf(x2, x3)));
    float tau = mx - 1.0f;
    #define P10(v, tt) ({ float z_ = fmaxf((v) - (tt), 0.f); float z2 = z_*z_; float z4 = z2*z2; float z8 = z4*z4; z8*z2; })
    float s0 = P10(x0, tau) + P10(x1, tau) + P10(x2, tau) + P10(x3, tau);
    float f_lo = wsum_dpp(s0) - 1.0f;
    float dm   = (mx - 0.58870401f) - tau;
    for (int itn = 0; itn < NITER; ++itn) {
        dm *= 0.5f;
        float tm = tau + dm;
        float s = P10(x0, tm) + P10(x1, tm) + P10(x2, tm) + P10(x3, tm);
        float fm = wsum_dpp(s) - 1.0f;
        if (fm * f_lo >= 0.0f) tau = tm;
    }
    float p0 = P10(x0, tau);
    float p1 = P10(x1, tau);
    float p2 = P10(x2, tau);
    float p3 = P10(x3, tau);
    #undef P10
    float sinv = 1.0f / wsum_dpp(p0 + p1 + p2 + p3);
    xs[r][lane]       = p0 * sinv;
    xs[r][lane + 64]  = p1 * sinv;
    xs[r][lane + 128] = p2 * sinv;
    if (lane < 16) xs[r][192 + lane] = p3 * sinv;
    __syncthreads();

    const int J0 = r * 50;
    float pj0 = (lane < 50) ? xs[0][J0 + lane] : 0.f;
    float pj1 = (lane < 50) ? xs[1][J0 + lane] : 0.f;
    float pj2 = (lane < 50) ? xs[2][J0 + lane] : 0.f;
    float pj3 = (lane < 50) ? xs[3][J0 + lane] : 0.f;
    float2 ov0 = {0.f,0.f}, ov1 = {0.f,0.f}, ov2 = {0.f,0.f}, ov3 = {0.f,0.f};
    {
        const float* hjb = hb + (size_t)J0 * DIMH + d2;
        #pragma unroll 5
        for (int jj = 0; jj < 50; ++jj) {
            float2 hv = *(const float2*)(hjb + jj * DIMH);
            float c0 = rdlane(pj0, jj), c1 = rdlane(pj1, jj);
            float c2 = rdlane(pj2, jj), c3 = rdlane(pj3, jj);
            ov0.x = fmaf(c0, hv.x, ov0.x); ov0.y = fmaf(c0, hv.y, ov0.y);
            ov1.x = fmaf(c1, hv.x, ov1.x); ov1.y = fmaf(c1, hv.y, ov1.y);
            ov2.x = fmaf(c2, hv.x, ov2.x); ov2.y = fmaf(c2, hv.y, ov2.y);
            ov3.x = fmaf(c3, hv.x, ov3.x); ov3.y = fmaf(c3, hv.y, ov3.y);
        }
    }
    *(float2*)&scrf[(r * 4 + 0) * DIMH + d2] = ov0;
    *(float2*)&scrf[(r * 4 + 1) * DIMH + d2] = ov1;
    *(float2*)&scrf[(r * 4 + 2) * DIMH + d2] = ov2;
    *(float2*)&scrf[(r * 4 + 3) * DIMH + d2] = ov3;
    __syncthreads();
    float2 o;
    {
        float2 q0 = *(const float2*)&scrf[(0 * 4 + r) * DIMH + d2];
        float2 q1 = *(const float2*)&scrf[(1 * 4 + r) * DIMH + d2];
        float2 q2 = *(const float2*)&scrf[(2 * 4 + r) * DIMH + d2];
        float2 q3 = *(const float2*)&scrf[(3 * 4 + r) * DIMH + d2];
        o.x = (q0.x + q1.x) + (q2.x + q3.x);
        o.y = (q0.y + q1.y) + (q2.y + q3.y);
    }
    *(float2*)&cop[r][DIMH + d2] = o;
    __syncthreads();

    float2 ov = *(const float2*)&cop[r][DIMH + d2];
    float cv0 = cop[0][64 * r + lane];
    float cv1 = cop[1][64 * r + lane];
    float cv2 = cop[2][64 * r + lane];
    float cv3 = cop[3][64 * r + lane];
    float2 gv0 = {0.f,0.f}, gv1 = {0.f,0.f}, gv2 = {0.f,0.f}, gv3 = {0.f,0.f};
    {
        const float* wb = W + (size_t)(64 * r) * DIMH + d2;
        #pragma unroll 8
        for (int ee = 0; ee < 64; ++ee) {
            float2 wv = *(const float2*)(wb + ee * DIMH);
            float c0 = rdlane(cv0, ee), c1 = rdlane(cv1, ee);
            float c2 = rdlane(cv2, ee), c3 = rdlane(cv3, ee);
            gv0.x = fmaf(c0, wv.x, gv0.x); gv0.y = fmaf(c0, wv.y, gv0.y);
            gv1.x = fmaf(c1, wv.x, gv1.x); gv1.y = fmaf(c1, wv.y, gv1.y);
            gv2.x = fmaf(c2, wv.x, gv2.x); gv2.y = fmaf(c2, wv.y, gv2.y);
            gv3.x = fmaf(c3, wv.x, gv3.x); gv3.y = fmaf(c3, wv.y, gv3.y);
        }
    }
    *(float2*)&scrf[(r * 4 + 0) * DIMH + d2] = gv0;
    *(float2*)&scrf[(r * 4 + 1) * DIMH + d2] = gv1;
    *(float2*)&scrf[(r * 4 + 2) * DIMH + d2] = gv2;
    *(float2*)&scrf[(r * 4 + 3) * DIMH + d2] = gv3;
    __syncthreads();
    {
        float2 q0 = *(const float2*)&scrf[(0 * 4 + r) * DIMH + d2];
        float2 q1 = *(const float2*)&scrf[(1 * 4 + r) * DIMH + d2];
        float2 q2 = *(const float2*)&scrf[(2 * 4 + r) * DIMH + d2];
        float2 q3 = *(const float2*)&scrf[(3 * 4 + r) * DIMH + d2];
        float2 bv = *(const float2*)(bias + d2);
        float gx = ((q0.x + q1.x) + (q2.x + q3.x)) + bv.x;
        float gy = ((q0.y + q1.y) + (q2.y + q3.y)) + bv.y;
        float sgx = 1.0f / (1.0f + __expf(-gx));
        float sgy = 1.0f / (1.0f + __expf(-gy));
        float2 hf = *(const float2*)&cop[r][d2];
        const size_t gi = (size_t)(b * NB + i0 + r) * DIMH;
        float2 res;
        res.x = sgx * ov.x + (1.0f - sgx) * hf.x;
        res.y = sgy * ov.y + (1.0f - sgy) * hf.y;
        *(float2*)(out + gi + d2) = res;
    }
}

extern "C" void kernel_launch(void* const* d_in, const int* in_sizes, int n_in,
                              void* d_out, int out_size, void* d_ws, size_t ws_size,
                              hipStream_t stream)
{
    const float* hidden = (const float*)d_in[0];
    const int*   adj    = (const int*)d_in[1];
    const int*   mask   = (const int*)d_in[2];
    const float* a0     = (const float*)d_in[3];
    const float* a1     = (const float*)d_in[4];
    const float* a2     = (const float*)d_in[5];
    const float* a3     = (const float*)d_in[6];
    const float* W      = (const float*)d_in[7];
    const float* bias   = (const float*)d_in[8];
    float* out = (float*)d_out;

    const int B = in_sizes[0] / (NB * DIMH);   // 256
    const int NBLK = B * (NB / ROWS8);         // 6400

    const size_t hsN = (size_t)B * NB * 64;
    const size_t htN = (size_t)B * DIMH * KJ2;
    const size_t tblU32  = (size_t)WF_U32 + 2 * hsN + 2 * htN;  // ht_lo slot reserved
    const size_t pwsN    = (size_t)NBLK * PBLK;
    const size_t fullU32 = tblU32 + pwsN;

    if (ws_size >= fullU32 * sizeof(unsigned)) {
        unsigned* wf    = (unsigned*)d_ws;
        unsigned* hs_hi = wf + WF_U32;
        unsigned* hs_lo = hs_hi + hsN;
        unsigned* ht_hi = hs_lo + hsN;
        unsigned* pws   = ht_hi + 2 * htN;
        conv_w<<<64, 64, 0, stream>>>(W, wf);
        conv_hs<<<(unsigned)(hsN / 256), 256, 0, stream>>>(hidden, hs_hi, hs_lo);
        conv_ht<<<B * 28, 256, 0, stream>>>(hidden, ht_hi);
        la_score<<<NBLK, TPB8, 0, stream>>>(hidden, adj, mask, a0, a1, a2, a3,
                                            hs_hi, hs_lo, pws);
        la_pvgate<<<NBLK, TPB8, 0, stream>>>(hidden, bias, wf, ht_hi, pws, out);
    } else if (ws_size >= tblU32 * sizeof(unsigned)) {
        unsigned* wf    = (unsigned*)d_ws;
        unsigned* hs_hi = wf + WF_U32;
        unsigned* hs_lo = hs_hi + hsN;
        unsigned* ht_hi = hs_lo + hsN;
        conv_w<<<64, 64, 0, stream>>>(W, wf);
        conv_hs<<<(unsigned)(hsN / 256), 256, 0, stream>>>(hidden, hs_hi, hs_lo);
        conv_ht<<<B * 28, 256, 0, stream>>>(hidden, ht_hi);
        la_fused8<<<NBLK, TPB8, 0, stream>>>(hidden, adj, mask, a0, a1, a2, a3,
                                             bias, wf, hs_hi, hs_lo, ht_hi, out);
    } else {
        la_basic<<<B * (NB / ROWS), TPB, 0, stream>>>(hidden, adj, mask,
                                                      a0, a1, a2, a3, W, bias, out);
    }
}

// Round 19
// 196.650 us; speedup vs baseline: 1.2498x; 1.2498x over previous
//
#include <hip/hip_runtime.h>
#include <math.h>

#define NB    200
#define DIMH  128
#define TPB8  512
#define ROWS8 8
#define NNEWT 4    // Newton on ||.||_10: quadratic, monotone from tau_lo; 4 iters ~1e-5
#define NITER 12   // fallback kernel
#define NJT   13   // j-tiles of 16 covering 208
#define KJ2   112  // padded j-pairs for PV (224 j's)

typedef __attribute__((ext_vector_type(8))) short  short8v;
typedef __attribute__((ext_vector_type(4))) float  f32x4;
typedef __attribute__((ext_vector_type(4))) unsigned u32x4;

#define WF_U32 32768   // W-frag table: hi + lo halves

__device__ __forceinline__ unsigned pack_hi2(float a, float b){
    return (__builtin_bit_cast(unsigned, a) >> 16) |
           (__builtin_bit_cast(unsigned, b) & 0xFFFF0000u);
}
__device__ __forceinline__ float hi_of(float x){
    return __builtin_bit_cast(float, __builtin_bit_cast(unsigned, x) & 0xFFFF0000u);
}
__device__ __forceinline__ float rdlane(float v, int l){
    return __builtin_bit_cast(float,
        __builtin_amdgcn_readlane(__builtin_bit_cast(int, v), l));
}
__device__ __forceinline__ float wsum_dpp(float v){
#define DPP_ADD(ctrl, rmask)                                                     \
    {                                                                            \
        int t_ = __builtin_amdgcn_update_dpp(0, __builtin_bit_cast(int, v),      \
                                             ctrl, rmask, 0xf, false);           \
        v += __builtin_bit_cast(float, t_);                                      \
    }
    DPP_ADD(0x111, 0xf)
    DPP_ADD(0x112, 0xf)
    DPP_ADD(0x114, 0xf)
    DPP_ADD(0x118, 0xf)
    DPP_ADD(0x142, 0xa)
    DPP_ADD(0x143, 0xc)
#undef DPP_ADD
    return rdlane(v, 63);
}
__device__ __forceinline__ void wsum2_dpp(float& a, float& b){
#define DPP2(ctrl, rmask)                                                        \
    {                                                                            \
        int ta = __builtin_amdgcn_update_dpp(0, __builtin_bit_cast(int, a),      \
                                             ctrl, rmask, 0xf, false);           \
        int tb = __builtin_amdgcn_update_dpp(0, __builtin_bit_cast(int, b),      \
                                             ctrl, rmask, 0xf, false);           \
        a += __builtin_bit_cast(float, ta);                                      \
        b += __builtin_bit_cast(float, tb);                                      \
    }
    DPP2(0x111, 0xf)
    DPP2(0x112, 0xf)
    DPP2(0x114, 0xf)
    DPP2(0x118, 0xf)
    DPP2(0x142, 0xa)
    DPP2(0x143, 0xc)
#undef DPP2
    a = rdlane(a, 63);
    b = rdlane(b, 63);
}
__device__ __forceinline__ float wmax_dpp(float v){
#define DPP_MAX(ctrl, rmask)                                                     \
    {                                                                            \
        int t_ = __builtin_amdgcn_update_dpp(__builtin_bit_cast(int, v),         \
                                             __builtin_bit_cast(int, v),         \
                                             ctrl, rmask, 0xf, false);           \
        v = fmaxf(v, __builtin_bit_cast(float, t_));                             \
    }
    DPP_MAX(0x111, 0xf)
    DPP_MAX(0x112, 0xf)
    DPP_MAX(0x114, 0xf)
    DPP_MAX(0x118, 0xf)
    DPP_MAX(0x142, 0xa)
    DPP_MAX(0x143, 0xc)
#undef DPP_MAX
    return rdlane(v, 63);
}

// One-time W -> bf16 hi/lo fragment table (gate MFMA B layout). Validated r10/r11.
__global__ __launch_bounds__(64) void conv_w(const float* __restrict__ W,
                                             unsigned* __restrict__ wf){
    const int lane = threadIdx.x;
    const int ks = blockIdx.x & 7, nt = blockIdx.x >> 3;
    const int krow = ks * 32 + (lane >> 4) * 8;
    const int col  = nt * 16 + (lane & 15);
    unsigned hi[4], lo[4];
    #pragma unroll
    for (int q2 = 0; q2 < 4; ++q2) {
        float v0 = W[(size_t)(krow + 2 * q2) * DIMH + col];
        float v1 = W[(size_t)(krow + 2 * q2 + 1) * DIMH + col];
        hi[q2] = pack_hi2(v0, v1);
        lo[q2] = pack_hi2(v0 - hi_of(v0), v1 - hi_of(v1));
    }
    const unsigned base = (blockIdx.x * 64 + lane) * 4;
    *(u32x4*)&wf[base]              = (u32x4){hi[0], hi[1], hi[2], hi[3]};
    *(u32x4*)&wf[WF_U32 / 2 + base] = (u32x4){lo[0], lo[1], lo[2], lo[3]};
}

// hidden -> hs[b][j][d2] bf16 hi/lo (score B layout). Validated r11.
__global__ __launch_bounds__(256) void conv_hs(const float* __restrict__ hidden,
                                               unsigned* __restrict__ hs_hi,
                                               unsigned* __restrict__ hs_lo){
    size_t gid = (size_t)blockIdx.x * 256 + threadIdx.x;
    float2 h2 = *(const float2*)(hidden + gid * 2);
    hs_hi[gid] = pack_hi2(h2.x, h2.y);
    hs_lo[gid] = pack_hi2(h2.x - hi_of(h2.x), h2.y - hi_of(h2.y));
}

// hidden -> ht[b][d][j2] bf16 (transposed, padded to 224 j: PV B layout, hi only).
__global__ __launch_bounds__(256) void conv_ht(const float* __restrict__ hidden,
                                               unsigned* __restrict__ ht_hi){
    __shared__ float tile[32][33];
    const int bid = blockIdx.x;
    const int b  = bid / 28;
    const int rem = bid % 28;
    const int jt = rem >> 2, dt = rem & 3;
    const int j0 = jt * 32, d0 = dt * 32;
    const int tt = threadIdx.x;
    #pragma unroll
    for (int rr = 0; rr < 4; ++rr) {
        int j = j0 + (tt >> 5) + rr * 8;
        int d = d0 + (tt & 31);
        tile[(tt >> 5) + rr * 8][tt & 31] =
            (j < NB) ? hidden[((size_t)b * NB + j) * DIMH + d] : 0.0f;
    }
    __syncthreads();
    #pragma unroll
    for (int it = 0; it < 2; ++it) {
        int j2 = it * 8 + (tt & 7);
        int dl = tt >> 3;
        float v0 = tile[2 * j2][dl];
        float v1 = tile[2 * j2 + 1][dl];
        size_t o = ((size_t)b * DIMH + d0 + dl) * KJ2 + (j0 >> 1) + j2;
        ht_hi[o] = pack_hi2(v0, v1);
    }
}

// r19: best fused structure (r17) + A-hi-only score (16 MFMA/jt, half staging)
// + NNEWT=4. LDS ~31.5KB -> 5 blocks/CU.
__global__ __launch_bounds__(TPB8, 4) void la_fused8(
    const float* __restrict__ hidden,
    const int*   __restrict__ adj,
    const int*   __restrict__ mask,
    const float* __restrict__ a0, const float* __restrict__ a1,
    const float* __restrict__ a2, const float* __restrict__ a3,
    const float* __restrict__ bias,
    const unsigned* __restrict__ wf,
    const unsigned* __restrict__ hs_hi, const unsigned* __restrict__ hs_lo,
    const unsigned* __restrict__ ht_hi,
    float* __restrict__ out)
{
    __shared__ __align__(16) unsigned hab[32][68];      // A hi only: 8704 B
    __shared__ float xs[ROWS8][208];                    // 6656 B
    __shared__ float cop[ROWS8][256];                   // 8192 B
    __shared__ __align__(16) unsigned ucb[2 * ROWS8 * 132];  // pbf/cbf union: 8448 B

    unsigned* pbf = ucb;
    #define CBF(part, row, idx) ucb[(part) * (ROWS8 * 132) + (row) * 132 + (idx)]

    const int t    = threadIdx.x;
    const int lane = t & 63;
    const int r    = t >> 6;
    const int d2   = 2 * lane;
    // XCD swizzle: 6400 = 8 x 800; 800 % 25 == 0 -> batch stays on one XCD L2.
    const int bid  = (blockIdx.x & 7) * ((int)gridDim.x >> 3) + (blockIdx.x >> 3);
    const int b    = bid / (NB / ROWS8);
    const int i0   = (bid % (NB / ROWS8)) * ROWS8;

    const float* hb = hidden + (size_t)b * NB * DIMH;

    // ---- stage h rows (cop) and A-hi table ----
    for (int idx = t; idx < ROWS8 * DIMH; idx += TPB8) {
        int rr = idx >> 7, d = idx & 127;
        cop[rr][d] = hb[(i0 + rr) * DIMH + d];
    }
    for (int s = t; s < 32 * 64; s += TPB8) {           // 2048 u32 over 512 thr = 4 iters
        int rk = s >> 6, dd = s & 63;
        int rr = rk >> 2, k = rk & 3;
        int d  = dd * 2;
        const float* ap = (k == 0) ? a0 : (k == 1) ? a1 : (k == 2) ? a2 : a3;
        float2 h2 = *(const float2*)(hb + (i0 + rr) * DIMH + d);
        float2 a2v = *(const float2*)(ap + d);
        hab[rk][dd] = pack_hi2(h2.x * a2v.x, h2.y * a2v.y);
    }
    __syncthreads();                                   // A

    // ---- A-frags for both 16-row tiles (hi only) ----
    short8v Ahi[2][4];
    {
        const int au = (lane >> 4) * 4;
        #pragma unroll
        for (int tl = 0; tl < 2; ++tl) {
            const int arow = tl * 16 + (lane & 15);
            #pragma unroll
            for (int ks = 0; ks < 4; ++ks)
                Ahi[tl][ks] = __builtin_bit_cast(short8v, *(const u32x4*)&hab[arow][ks * 16 + au]);
        }
    }

    // ---- score via MFMA: wave r does jt = r, r+8; Ahi x (Bh + Bl) = 2 MFMA/ks/tile ----
    const int jcol = lane & 15;
    const int kgrp = lane >> 4;
    for (int jt = r; jt < NJT; jt += 8) {
        const int jrow = jt * 16 + jcol;
        const int jl   = (jrow < NB) ? jrow : (NB - 1);
        f32x4 acc0 = {0.f, 0.f, 0.f, 0.f};
        f32x4 acc1 = {0.f, 0.f, 0.f, 0.f};
        const unsigned* bhp = hs_hi + ((size_t)(b * NB + jl) << 6) + kgrp * 4;
        const unsigned* blp = hs_lo + ((size_t)(b * NB + jl) << 6) + kgrp * 4;
        #pragma unroll
        for (int ks = 0; ks < 4; ++ks) {
            short8v Bh = __builtin_bit_cast(short8v, *(const u32x4*)(bhp + ks * 16));
            short8v Bl = __builtin_bit_cast(short8v, *(const u32x4*)(blp + ks * 16));
            acc0 = __builtin_amdgcn_mfma_f32_16x16x32_bf16(Ahi[0][ks], Bh, acc0, 0, 0, 0);
            acc0 = __builtin_amdgcn_mfma_f32_16x16x32_bf16(Ahi[0][ks], Bl, acc0, 0, 0, 0);
            acc1 = __builtin_amdgcn_mfma_f32_16x16x32_bf16(Ahi[1][ks], Bh, acc1, 0, 0, 0);
            acc1 = __builtin_amdgcn_mfma_f32_16x16x32_bf16(Ahi[1][ks], Bl, acc1, 0, 0, 0);
        }
        const int mm  = mask[b * NB + jl];
        const int kk0 = adj[(size_t)(b * NB + i0 + kgrp) * NB + jl];
        const int kk1 = adj[(size_t)(b * NB + i0 + 4 + kgrp) * NB + jl];
        float ev0 = (kk0 == 1) ? acc0[0] : (kk0 == 2) ? acc0[1] :
                    (kk0 == 3) ? acc0[2] : (kk0 == 4) ? acc0[3] : 0.0f;
        float ev1 = (kk1 == 1) ? acc1[0] : (kk1 == 2) ? acc1[1] :
                    (kk1 == 3) ? acc1[2] : (kk1 == 4) ? acc1[3] : 0.0f;
        ev0 = (ev0 >= 0.0f) ? ev0 : 0.2f * ev0;        // leaky relu 0.2
        ev1 = (ev1 >= 0.0f) ? ev1 : 0.2f * ev1;
        float xv0 = ev0 * 0.1f;                        // * (alpha-1)
        float xv1 = ev1 * 0.1f;
        if (mm == 0 || jrow >= NB) { xv0 = -INFINITY; xv1 = -INFINITY; }
        xs[kgrp][jrow]     = xv0;
        xs[4 + kgrp][jrow] = xv1;
    }
    __syncthreads();                                   // B

    // ---- entmax via Newton on ||(x-tau)+||_10 = 1 ----
    float x0 = xs[r][lane];
    float x1 = xs[r][lane + 64];
    float x2 = xs[r][lane + 128];
    float x3 = (lane < 16) ? xs[r][192 + lane] : -INFINITY;

    float mx  = wmax_dpp(fmaxf(fmaxf(x0, x1), fmaxf(x2, x3)));
    float tau = mx - 1.0f;
    #pragma unroll
    for (int itn = 0; itn < NNEWT; ++itn) {
        float t10 = 0.f, t9 = 0.f;
        #define ACC(xv) { float z_ = fmaxf((xv) - tau, 0.f); float e2 = z_*z_;   \
                          float e8 = e2*e2; e8 = e8*e8; float e9 = e8*z_;        \
                          t9 += e9; t10 = fmaf(e9, z_, t10); }
        ACC(x0) ACC(x1) ACC(x2) ACC(x3)
        #undef ACC
        wsum2_dpp(t10, t9);
        float u  = exp2f(0.1f * log2f(t10));
        tau += t10 * (1.0f - __builtin_amdgcn_rcpf(u)) * __builtin_amdgcn_rcpf(t9);
    }
    #define P10(v, tt) ({ float z_ = fmaxf((v) - (tt), 0.f); float z2 = z_*z_; float z4 = z2*z2; float z8 = z4*z4; z8*z2; })
    float p0 = P10(x0, tau);
    float p1 = P10(x1, tau);
    float p2 = P10(x2, tau);
    float p3 = P10(x3, tau);
    #undef P10
    float sinv = 1.0f / wsum_dpp(p0 + p1 + p2 + p3);   // ensure_sum_one
    xs[r][lane]       = p0 * sinv;
    xs[r][lane + 64]  = p1 * sinv;
    xs[r][lane + 128] = p2 * sinv;
    if (lane < 16) xs[r][192 + lane] = p3 * sinv;

    // ---- pbf row r built wave-locally ----
    for (int k2 = lane; k2 < KJ2; k2 += 64) {
        int j = 2 * k2;
        float v0 = (j < 208)     ? xs[r][j]     : 0.0f;
        float v1 = (j + 1 < 208) ? xs[r][j + 1] : 0.0f;
        pbf[r * 116 + k2]                = pack_hi2(v0, v1);
        pbf[ROWS8 * 116 + r * 116 + k2]  = pack_hi2(v0 - hi_of(v0), v1 - hi_of(v1));
    }
    __syncthreads();                                   // C

    // ---- PV via MFMA: wave r does n-tile r; P hi/lo x H bf16 ----
    {
        f32x4 av = {0.f, 0.f, 0.f, 0.f};
        const int prow = lane & 7;
        const int au   = (lane >> 4) * 4;
        const int dc   = 16 * r + (lane & 15);
        const size_t base = ((size_t)(b * DIMH + dc)) * KJ2 + au;
        #pragma unroll
        for (int ks = 0; ks < 7; ++ks) {
            short8v Ph = __builtin_bit_cast(short8v, *(const u32x4*)&pbf[prow * 116 + ks * 16 + au]);
            short8v Pl = __builtin_bit_cast(short8v, *(const u32x4*)&pbf[ROWS8 * 116 + prow * 116 + ks * 16 + au]);
            short8v Bh = __builtin_bit_cast(short8v, *(const u32x4*)(ht_hi + base + ks * 16));
            av = __builtin_amdgcn_mfma_f32_16x16x32_bf16(Ph, Bh, av, 0, 0, 0);
            av = __builtin_amdgcn_mfma_f32_16x16x32_bf16(Pl, Bh, av, 0, 0, 0);
        }
        if (lane < 32) {
            const int rbase = (lane >> 4) * 4;
            #pragma unroll
            for (int q = 0; q < 4; ++q)
                cop[rbase + q][DIMH + 16 * r + (lane & 15)] = av[q];
        }
    }
    __syncthreads();                                   // E (pbf dead after this)

    float2 ovv = *(const float2*)&cop[r][DIMH + d2];

    // ---- gate via MFMA: C hi/lo x W bf16; wave r does n-tile r ----
    {
        float hx = cop[r][d2], hy = cop[r][d2 + 1];
        CBF(0, r, lane)      = pack_hi2(hx, hy);
        CBF(1, r, lane)      = pack_hi2(hx - hi_of(hx), hy - hi_of(hy));
        CBF(0, r, 64 + lane) = pack_hi2(ovv.x, ovv.y);
        CBF(1, r, 64 + lane) = pack_hi2(ovv.x - hi_of(ovv.x), ovv.y - hi_of(ovv.y));
    }
    __syncthreads();                                   // F

    {
        f32x4 ga = {0.f, 0.f, 0.f, 0.f};
        const int arow = lane & 7;
        const int au   = (lane >> 4) * 4;
        #pragma unroll
        for (int ks = 0; ks < 8; ++ks) {
            short8v Ah = __builtin_bit_cast(short8v, *(const u32x4*)&CBF(0, arow, ks * 16 + au));
            short8v Al = __builtin_bit_cast(short8v, *(const u32x4*)&CBF(1, arow, ks * 16 + au));
            const unsigned bi = ((r * 8 + ks) * 64 + lane) * 4;
            short8v Bh = __builtin_bit_cast(short8v, *(const u32x4*)&wf[bi]);
            ga = __builtin_amdgcn_mfma_f32_16x16x32_bf16(Ah, Bh, ga, 0, 0, 0);
            ga = __builtin_amdgcn_mfma_f32_16x16x32_bf16(Al, Bh, ga, 0, 0, 0);
        }
        if (lane < 32) {
            const int rbase = (lane >> 4) * 4;
            #pragma unroll
            for (int q = 0; q < 4; ++q)
                xs[rbase + q][16 * r + (lane & 15)] = ga[q];
        }
    }
    __syncthreads();                                   // G

    // ---- final ----
    {
        float2 bv = *(const float2*)(bias + d2);
        float gx = xs[r][d2]     + bv.x;
        float gy = xs[r][d2 + 1] + bv.y;
        float sgx = 1.0f / (1.0f + __expf(-gx));
        float sgy = 1.0f / (1.0f + __expf(-gy));
        float2 hf = *(const float2*)&cop[r][d2];
        const size_t gi = (size_t)(b * NB + i0 + r) * DIMH;
        float2 res;
        res.x = sgx * ovv.x + (1.0f - sgx) * hf.x;
        res.y = sgy * ovv.y + (1.0f - sgy) * hf.y;
        *(float2*)(out + gi + d2) = res;
    }
    #undef CBF
}

// ========== fallback: no-ws 4-row f32 kernel (round-9 structure) ==========
#define ROWS  4
#define TPB   256
__global__ __launch_bounds__(TPB, 4) void la_basic(
    const float* __restrict__ hidden,
    const int*   __restrict__ adj,
    const int*   __restrict__ mask,
    const float* __restrict__ a0, const float* __restrict__ a1,
    const float* __restrict__ a2, const float* __restrict__ a3,
    const float* __restrict__ W,  const float* __restrict__ bias,
    float* __restrict__ out)
{
    __shared__ float ha[ROWS][4][132];
    __shared__ float xs[ROWS][208];
    __shared__ float cop[ROWS][256];
    __shared__ float scrf[ROWS * ROWS * DIMH];

    const int t    = threadIdx.x;
    const int lane = t & 63;
    const int r    = t >> 6;
    const int d2   = 2 * lane;
    const int bid  = blockIdx.x;
    const int b    = bid / (NB / ROWS);
    const int i0   = (bid % (NB / ROWS)) * ROWS;

    const float* hb = hidden + (size_t)b * NB * DIMH;

    for (int idx = t; idx < ROWS * DIMH; idx += TPB) {
        int rr = idx >> 7, d = idx & 127;
        cop[rr][d] = hb[(i0 + rr) * DIMH + d];
    }
    for (int idx = t; idx < ROWS * 4 * DIMH; idx += TPB) {
        int rr = idx >> 9, k = (idx >> 7) & 3, d = idx & 127;
        float av = (k == 0) ? a0[d] : (k == 1) ? a1[d] : (k == 2) ? a2[d] : a3[d];
        ha[rr][k][d] = hb[(i0 + rr) * DIMH + d] * av;
    }
    __syncthreads();

    if (t < NB) {
        const int m = mask[b * NB + t];
        int kk[ROWS];
        #pragma unroll
        for (int rr = 0; rr < ROWS; rr++)
            kk[rr] = adj[((size_t)(b * NB + i0 + rr)) * NB + t];
        int ksel[ROWS];
        #pragma unroll
        for (int rr = 0; rr < ROWS; rr++) ksel[rr] = (kk[rr] > 0) ? (kk[rr] - 1) : 0;
        float acc[ROWS] = {0.f, 0.f, 0.f, 0.f};
        const float* hj = hb + t * DIMH;
        #pragma unroll 4
        for (int d = 0; d < DIMH; d += 4) {
            float4 hv = *(const float4*)(hj + d);
            #pragma unroll
            for (int rr = 0; rr < ROWS; rr++) {
                const float4 av4 = *(const float4*)&ha[rr][ksel[rr]][d];
                acc[rr] = fmaf(hv.x, av4.x, acc[rr]);
                acc[rr] = fmaf(hv.y, av4.y, acc[rr]);
                acc[rr] = fmaf(hv.z, av4.z, acc[rr]);
                acc[rr] = fmaf(hv.w, av4.w, acc[rr]);
            }
        }
        #pragma unroll
        for (int rr = 0; rr < ROWS; rr++) {
            float x;
            if (m == 0)           x = -INFINITY;
            else if (kk[rr] == 0) x = 0.0f;
            else {
                float e = acc[rr];
                e = (e >= 0.0f) ? e : 0.2f * e;
                x = e * 0.1f;
            }
            xs[rr][t] = x;
        }
    } else if (t < 208) {
        #pragma unroll
        for (int rr = 0; rr < ROWS; rr++) xs[rr][t] = -INFINITY;
    }
    __syncthreads();

    float x0 = xs[r][lane];
    float x1 = xs[r][lane + 64];
    float x2 = xs[r][lane + 128];
    float x3 = (lane < 16) ? xs[r][192 + lane] : -INFINITY;

    float mx  = wmax_dpp(fmaxf(fmaxf(x0, x1), fmaxf(x2, x3)));
    float tau = mx - 1.0f;
    #define P10(v, tt) ({ float z_ = fmaxf((v) - (tt), 0.f); float z2 = z_*z_; float z4 = z2*z2; float z8 = z4*z4; z8*z2; })
    float s0 = P10(x0, tau) + P10(x1, tau) + P10(x2, tau) + P10(x3, tau);
    float f_lo = wsum_dpp(s0) - 1.0f;
    float dm   = (mx - 0.58870401f) - tau;
    for (int itn = 0; itn < NITER; ++itn) {
        dm *= 0.5f;
        float tm = tau + dm;
        float s = P10(x0, tm) + P10(x1, tm) + P10(x2, tm) + P10(x3, tm);
        float fm = wsum_dpp(s) - 1.0f;
        if (fm * f_lo >= 0.0f) tau = tm;
    }
    float p0 = P10(x0, tau);
    float p1 = P10(x1, tau);
    float p2 = P10(x2, tau);
    float p3 = P10(x3, tau);
    #undef P10
    float sinv = 1.0f / wsum_dpp(p0 + p1 + p2 + p3);
    xs[r][lane]       = p0 * sinv;
    xs[r][lane + 64]  = p1 * sinv;
    xs[r][lane + 128] = p2 * sinv;
    if (lane < 16) xs[r][192 + lane] = p3 * sinv;
    __syncthreads();

    const int J0 = r * 50;
    float pj0 = (lane < 50) ? xs[0][J0 + lane] : 0.f;
    float pj1 = (lane < 50) ? xs[1][J0 + lane] : 0.f;
    float pj2 = (lane < 50) ? xs[2][J0 + lane] : 0.f;
    float pj3 = (lane < 50) ? xs[3][J0 + lane] : 0.f;
    float2 ov0 = {0.f,0.f}, ov1 = {0.f,0.f}, ov2 = {0.f,0.f}, ov3 = {0.f,0.f};
    {
        const float* hjb = hb + (size_t)J0 * DIMH + d2;
        #pragma unroll 5
        for (int jj = 0; jj < 50; ++jj) {
            float2 hv = *(const float2*)(hjb + jj * DIMH);
            float c0 = rdlane(pj0, jj), c1 = rdlane(pj1, jj);
            float c2 = rdlane(pj2, jj), c3 = rdlane(pj3, jj);
            ov0.x = fmaf(c0, hv.x, ov0.x); ov0.y = fmaf(c0, hv.y, ov0.y);
            ov1.x = fmaf(c1, hv.x, ov1.x); ov1.y = fmaf(c1, hv.y, ov1.y);
            ov2.x = fmaf(c2, hv.x, ov2.x); ov2.y = fmaf(c2, hv.y, ov2.y);
            ov3.x = fmaf(c3, hv.x, ov3.x); ov3.y = fmaf(c3, hv.y, ov3.y);
        }
    }
    *(float2*)&scrf[(r * 4 + 0) * DIMH + d2] = ov0;
    *(float2*)&scrf[(r * 4 + 1) * DIMH + d2] = ov1;
    *(float2*)&scrf[(r * 4 + 2) * DIMH + d2] = ov2;
    *(float2*)&scrf[(r * 4 + 3) * DIMH + d2] = ov3;
    __syncthreads();
    float2 o;
    {
        float2 q0 = *(const float2*)&scrf[(0 * 4 + r) * DIMH + d2];
        float2 q1 = *(const float2*)&scrf[(1 * 4 + r) * DIMH + d2];
        float2 q2 = *(const float2*)&scrf[(2 * 4 + r) * DIMH + d2];
        float2 q3 = *(const float2*)&scrf[(3 * 4 + r) * DIMH + d2];
        o.x = (q0.x + q1.x) + (q2.x + q3.x);
        o.y = (q0.y + q1.y) + (q2.y + q3.y);
    }
    *(float2*)&cop[r][DIMH + d2] = o;
    __syncthreads();

    float2 ov = *(const float2*)&cop[r][DIMH + d2];
    float cv0 = cop[0][64 * r + lane];
    float cv1 = cop[1][64 * r + lane];
    float cv2 = cop[2][64 * r + lane];
    float cv3 = cop[3][64 * r + lane];
    float2 gv0 = {0.f,0.f}, gv1 = {0.f,0.f}, gv2 = {0.f,0.f}, gv3 = {0.f,0.f};
    {
        const float* wb = W + (size_t)(64 * r) * DIMH + d2;
        #pragma unroll 8
        for (int ee = 0; ee < 64; ++ee) {
            float2 wv = *(const float2*)(wb + ee * DIMH);
            float c0 = rdlane(cv0, ee), c1 = rdlane(cv1, ee);
            float c2 = rdlane(cv2, ee), c3 = rdlane(cv3, ee);
            gv0.x = fmaf(c0, wv.x, gv0.x); gv0.y = fmaf(c0, wv.y, gv0.y);
            gv1.x = fmaf(c1, wv.x, gv1.x); gv1.y = fmaf(c1, wv.y, gv1.y);
            gv2.x = fmaf(c2, wv.x, gv2.x); gv2.y = fmaf(c2, wv.y, gv2.y);
            gv3.x = fmaf(c3, wv.x, gv3.x); gv3.y = fmaf(c3, wv.y, gv3.y);
        }
    }
    *(float2*)&scrf[(r * 4 + 0) * DIMH + d2] = gv0;
    *(float2*)&scrf[(r * 4 + 1) * DIMH + d2] = gv1;
    *(float2*)&scrf[(r * 4 + 2) * DIMH + d2] = gv2;
    *(float2*)&scrf[(r * 4 + 3) * DIMH + d2] = gv3;
    __syncthreads();
    {
        float2 q0 = *(const float2*)&scrf[(0 * 4 + r) * DIMH + d2];
        float2 q1 = *(const float2*)&scrf[(1 * 4 + r) * DIMH + d2];
        float2 q2 = *(const float2*)&scrf[(2 * 4 + r) * DIMH + d2];
        float2 q3 = *(const float2*)&scrf[(3 * 4 + r) * DIMH + d2];
        float2 bv = *(const float2*)(bias + d2);
        float gx = ((q0.x + q1.x) + (q2.x + q3.x)) + bv.x;
        float gy = ((q0.y + q1.y) + (q2.y + q3.y)) + bv.y;
        float sgx = 1.0f / (1.0f + __expf(-gx));
        float sgy = 1.0f / (1.0f + __expf(-gy));
        float2 hf = *(const float2*)&cop[r][d2];
        const size_t gi = (size_t)(b * NB + i0 + r) * DIMH;
        float2 res;
        res.x = sgx * ov.x + (1.0f - sgx) * hf.x;
        res.y = sgy * ov.y + (1.0f - sgy) * hf.y;
        *(float2*)(out + gi + d2) = res;
    }
}

extern "C" void kernel_launch(void* const* d_in, const int* in_sizes, int n_in,
                              void* d_out, int out_size, void* d_ws, size_t ws_size,
                              hipStream_t stream)
{
    const float* hidden = (const float*)d_in[0];
    const int*   adj    = (const int*)d_in[1];
    const int*   mask   = (const int*)d_in[2];
    const float* a0     = (const float*)d_in[3];
    const float* a1     = (const float*)d_in[4];
    const float* a2     = (const float*)d_in[5];
    const float* a3     = (const float*)d_in[6];
    const float* W      = (const float*)d_in[7];
    const float* bias   = (const float*)d_in[8];
    float* out = (float*)d_out;

    const int B = in_sizes[0] / (NB * DIMH);   // 256
    const int NBLK = B * (NB / ROWS8);         // 6400

    const size_t hsN = (size_t)B * NB * 64;
    const size_t htN = (size_t)B * DIMH * KJ2;
    const size_t tblU32 = (size_t)WF_U32 + 2 * hsN + 2 * htN;  // ht_lo slot reserved

    if (ws_size >= tblU32 * sizeof(unsigned)) {
        unsigned* wf    = (unsigned*)d_ws;
        unsigned* hs_hi = wf + WF_U32;
        unsigned* hs_lo = hs_hi + hsN;
        unsigned* ht_hi = hs_lo + hsN;
        conv_w<<<64, 64, 0, stream>>>(W, wf);
        conv_hs<<<(unsigned)(hsN / 256), 256, 0, stream>>>(hidden, hs_hi, hs_lo);
        conv_ht<<<B * 28, 256, 0, stream>>>(hidden, ht_hi);
        la_fused8<<<NBLK, TPB8, 0, stream>>>(hidden, adj, mask, a0, a1, a2, a3,
                                             bias, wf, hs_hi, hs_lo, ht_hi, out);
    } else {
        la_basic<<<B * (NB / ROWS), TPB, 0, stream>>>(hidden, adj, mask,
                                                      a0, a1, a2, a3, W, bias, out);
    }
}

// Round 20
// 161.914 us; speedup vs baseline: 1.5180x; 1.2145x over previous
//
#include <hip/hip_runtime.h>
#include <math.h>

#define NB    200
#define DIMH  128
#define TPB8  512
#define ROWS8 8
#define NNEWT 4    // Newton on ||.||_10: quadratic, monotone from tau_lo
#define NITER 12   // fallback kernel
#define NJT   13   // j-tiles of 16 covering 208
#define KJ2   112  // padded j-pairs for PV (224 j's)

typedef __attribute__((ext_vector_type(8))) short  short8v;
typedef __attribute__((ext_vector_type(4))) float  f32x4;
typedef __attribute__((ext_vector_type(4))) unsigned u32x4;

#define WF_U32 32768   // W-frag table: hi + lo halves

__device__ __forceinline__ unsigned pack_hi2(float a, float b){
    return (__builtin_bit_cast(unsigned, a) >> 16) |
           (__builtin_bit_cast(unsigned, b) & 0xFFFF0000u);
}
__device__ __forceinline__ float hi_of(float x){
    return __builtin_bit_cast(float, __builtin_bit_cast(unsigned, x) & 0xFFFF0000u);
}
__device__ __forceinline__ float rdlane(float v, int l){
    return __builtin_bit_cast(float,
        __builtin_amdgcn_readlane(__builtin_bit_cast(int, v), l));
}
__device__ __forceinline__ float wsum_dpp(float v){
#define DPP_ADD(ctrl, rmask)                                                     \
    {                                                                            \
        int t_ = __builtin_amdgcn_update_dpp(0, __builtin_bit_cast(int, v),      \
                                             ctrl, rmask, 0xf, false);           \
        v += __builtin_bit_cast(float, t_);                                      \
    }
    DPP_ADD(0x111, 0xf)
    DPP_ADD(0x112, 0xf)
    DPP_ADD(0x114, 0xf)
    DPP_ADD(0x118, 0xf)
    DPP_ADD(0x142, 0xa)
    DPP_ADD(0x143, 0xc)
#undef DPP_ADD
    return rdlane(v, 63);
}
__device__ __forceinline__ void wsum2_dpp(float& a, float& b){
#define DPP2(ctrl, rmask)                                                        \
    {                                                                            \
        int ta = __builtin_amdgcn_update_dpp(0, __builtin_bit_cast(int, a),      \
                                             ctrl, rmask, 0xf, false);           \
        int tb = __builtin_amdgcn_update_dpp(0, __builtin_bit_cast(int, b),      \
                                             ctrl, rmask, 0xf, false);           \
        a += __builtin_bit_cast(float, ta);                                      \
        b += __builtin_bit_cast(float, tb);                                      \
    }
    DPP2(0x111, 0xf)
    DPP2(0x112, 0xf)
    DPP2(0x114, 0xf)
    DPP2(0x118, 0xf)
    DPP2(0x142, 0xa)
    DPP2(0x143, 0xc)
#undef DPP2
    a = rdlane(a, 63);
    b = rdlane(b, 63);
}
__device__ __forceinline__ float wmax_dpp(float v){
#define DPP_MAX(ctrl, rmask)                                                     \
    {                                                                            \
        int t_ = __builtin_amdgcn_update_dpp(__builtin_bit_cast(int, v),         \
                                             __builtin_bit_cast(int, v),         \
                                             ctrl, rmask, 0xf, false);           \
        v = fmaxf(v, __builtin_bit_cast(float, t_));                             \
    }
    DPP_MAX(0x111, 0xf)
    DPP_MAX(0x112, 0xf)
    DPP_MAX(0x114, 0xf)
    DPP_MAX(0x118, 0xf)
    DPP_MAX(0x142, 0xa)
    DPP_MAX(0x143, 0xc)
#undef DPP_MAX
    return rdlane(v, 63);
}

// One-time W -> bf16 hi/lo fragment table (gate MFMA B layout). Validated r10/r11.
__global__ __launch_bounds__(64) void conv_w(const float* __restrict__ W,
                                             unsigned* __restrict__ wf){
    const int lane = threadIdx.x;
    const int ks = blockIdx.x & 7, nt = blockIdx.x >> 3;
    const int krow = ks * 32 + (lane >> 4) * 8;
    const int col  = nt * 16 + (lane & 15);
    unsigned hi[4], lo[4];
    #pragma unroll
    for (int q2 = 0; q2 < 4; ++q2) {
        float v0 = W[(size_t)(krow + 2 * q2) * DIMH + col];
        float v1 = W[(size_t)(krow + 2 * q2 + 1) * DIMH + col];
        hi[q2] = pack_hi2(v0, v1);
        lo[q2] = pack_hi2(v0 - hi_of(v0), v1 - hi_of(v1));
    }
    const unsigned base = (blockIdx.x * 64 + lane) * 4;
    *(u32x4*)&wf[base]              = (u32x4){hi[0], hi[1], hi[2], hi[3]};
    *(u32x4*)&wf[WF_U32 / 2 + base] = (u32x4){lo[0], lo[1], lo[2], lo[3]};
}

// hidden -> hs[b][j][d2] bf16 hi/lo (score B layout). Validated r11.
__global__ __launch_bounds__(256) void conv_hs(const float* __restrict__ hidden,
                                               unsigned* __restrict__ hs_hi,
                                               unsigned* __restrict__ hs_lo){
    size_t gid = (size_t)blockIdx.x * 256 + threadIdx.x;
    float2 h2 = *(const float2*)(hidden + gid * 2);
    hs_hi[gid] = pack_hi2(h2.x, h2.y);
    hs_lo[gid] = pack_hi2(h2.x - hi_of(h2.x), h2.y - hi_of(h2.y));
}

// hidden -> ht[b][d][j2] bf16 (transposed, padded to 224 j: PV B layout, hi only).
__global__ __launch_bounds__(256) void conv_ht(const float* __restrict__ hidden,
                                               unsigned* __restrict__ ht_hi){
    __shared__ float tile[32][33];
    const int bid = blockIdx.x;
    const int b  = bid / 28;
    const int rem = bid % 28;
    const int jt = rem >> 2, dt = rem & 3;
    const int j0 = jt * 32, d0 = dt * 32;
    const int tt = threadIdx.x;
    #pragma unroll
    for (int rr = 0; rr < 4; ++rr) {
        int j = j0 + (tt >> 5) + rr * 8;
        int d = d0 + (tt & 31);
        tile[(tt >> 5) + rr * 8][tt & 31] =
            (j < NB) ? hidden[((size_t)b * NB + j) * DIMH + d] : 0.0f;
    }
    __syncthreads();
    #pragma unroll
    for (int it = 0; it < 2; ++it) {
        int j2 = it * 8 + (tt & 7);
        int dl = tt >> 3;
        float v0 = tile[2 * j2][dl];
        float v1 = tile[2 * j2 + 1][dl];
        size_t o = ((size_t)b * DIMH + d0 + dl) * KJ2 + (j0 >> 1) + j2;
        ht_hi[o] = pack_hi2(v0, v1);
    }
}

// r20: r19 structure + cross-barrier prefetch (T14) on all three MFMA phases:
// score-B before barrier A, PV-B (ht) before entmax, gate-B (wf) before PV.
__global__ __launch_bounds__(TPB8, 4) void la_fused8(
    const float* __restrict__ hidden,
    const int*   __restrict__ adj,
    const int*   __restrict__ mask,
    const float* __restrict__ a0, const float* __restrict__ a1,
    const float* __restrict__ a2, const float* __restrict__ a3,
    const float* __restrict__ bias,
    const unsigned* __restrict__ wf,
    const unsigned* __restrict__ hs_hi, const unsigned* __restrict__ hs_lo,
    const unsigned* __restrict__ ht_hi,
    float* __restrict__ out)
{
    __shared__ __align__(16) unsigned hab[32][68];      // A hi only
    __shared__ float xs[ROWS8][208];
    __shared__ float cop[ROWS8][256];
    __shared__ __align__(16) unsigned ucb[2 * ROWS8 * 132];  // pbf/cbf union

    unsigned* pbf = ucb;
    #define CBF(part, row, idx) ucb[(part) * (ROWS8 * 132) + (row) * 132 + (idx)]

    const int t    = threadIdx.x;
    const int lane = t & 63;
    const int r    = t >> 6;
    const int d2   = 2 * lane;
    // XCD swizzle: 6400 = 8 x 800; 800 % 25 == 0 -> batch stays on one XCD L2.
    const int bid  = (blockIdx.x & 7) * ((int)gridDim.x >> 3) + (blockIdx.x >> 3);
    const int b    = bid / (NB / ROWS8);
    const int i0   = (bid % (NB / ROWS8)) * ROWS8;

    const float* hb = hidden + (size_t)b * NB * DIMH;
    const int jcol = lane & 15;
    const int kgrp = lane >> 4;

    // ==== PREFETCH 1: score B-frags + adj/mask for jt = r (jrow0 < 128, no clamp) ====
    const int jrow0 = r * 16 + jcol;
    u32x4 pBh[4], pBl[4];
    {
        const unsigned* bhp = hs_hi + ((size_t)(b * NB + jrow0) << 6) + kgrp * 4;
        const unsigned* blp = hs_lo + ((size_t)(b * NB + jrow0) << 6) + kgrp * 4;
        #pragma unroll
        for (int ks = 0; ks < 4; ++ks) {
            pBh[ks] = *(const u32x4*)(bhp + ks * 16);
            pBl[ks] = *(const u32x4*)(blp + ks * 16);
        }
    }
    const int mm0 = mask[b * NB + jrow0];
    const int a00 = adj[(size_t)(b * NB + i0 + kgrp) * NB + jrow0];
    const int a01 = adj[(size_t)(b * NB + i0 + 4 + kgrp) * NB + jrow0];

    // ---- stage h rows (cop) and A-hi table ----
    for (int idx = t; idx < ROWS8 * DIMH; idx += TPB8) {
        int rr = idx >> 7, d = idx & 127;
        cop[rr][d] = hb[(i0 + rr) * DIMH + d];
    }
    for (int s = t; s < 32 * 64; s += TPB8) {
        int rk = s >> 6, dd = s & 63;
        int rr = rk >> 2, k = rk & 3;
        int d  = dd * 2;
        const float* ap = (k == 0) ? a0 : (k == 1) ? a1 : (k == 2) ? a2 : a3;
        float2 h2 = *(const float2*)(hb + (i0 + rr) * DIMH + d);
        float2 a2v = *(const float2*)(ap + d);
        hab[rk][dd] = pack_hi2(h2.x * a2v.x, h2.y * a2v.y);
    }
    __syncthreads();                                   // A

    // ---- A-frags for both 16-row tiles (hi only) ----
    short8v Ahi[2][4];
    {
        const int au = (lane >> 4) * 4;
        #pragma unroll
        for (int tl = 0; tl < 2; ++tl) {
            const int arow = tl * 16 + (lane & 15);
            #pragma unroll
            for (int ks = 0; ks < 4; ++ks)
                Ahi[tl][ks] = __builtin_bit_cast(short8v, *(const u32x4*)&hab[arow][ks * 16 + au]);
        }
    }

    // ---- score iter 1: jt = r (operands prefetched; jrow0 always < NB) ----
    {
        f32x4 acc0 = {0.f, 0.f, 0.f, 0.f};
        f32x4 acc1 = {0.f, 0.f, 0.f, 0.f};
        #pragma unroll
        for (int ks = 0; ks < 4; ++ks) {
            short8v Bh = __builtin_bit_cast(short8v, pBh[ks]);
            short8v Bl = __builtin_bit_cast(short8v, pBl[ks]);
            acc0 = __builtin_amdgcn_mfma_f32_16x16x32_bf16(Ahi[0][ks], Bh, acc0, 0, 0, 0);
            acc0 = __builtin_amdgcn_mfma_f32_16x16x32_bf16(Ahi[0][ks], Bl, acc0, 0, 0, 0);
            acc1 = __builtin_amdgcn_mfma_f32_16x16x32_bf16(Ahi[1][ks], Bh, acc1, 0, 0, 0);
            acc1 = __builtin_amdgcn_mfma_f32_16x16x32_bf16(Ahi[1][ks], Bl, acc1, 0, 0, 0);
        }
        float ev0 = (a00 == 1) ? acc0[0] : (a00 == 2) ? acc0[1] :
                    (a00 == 3) ? acc0[2] : (a00 == 4) ? acc0[3] : 0.0f;
        float ev1 = (a01 == 1) ? acc1[0] : (a01 == 2) ? acc1[1] :
                    (a01 == 3) ? acc1[2] : (a01 == 4) ? acc1[3] : 0.0f;
        ev0 = (ev0 >= 0.0f) ? ev0 : 0.2f * ev0;        // leaky relu 0.2
        ev1 = (ev1 >= 0.0f) ? ev1 : 0.2f * ev1;
        float xv0 = ev0 * 0.1f;                        // * (alpha-1)
        float xv1 = ev1 * 0.1f;
        if (mm0 == 0) { xv0 = -INFINITY; xv1 = -INFINITY; }
        xs[kgrp][jrow0]     = xv0;
        xs[4 + kgrp][jrow0] = xv1;
    }

    // ---- score iter 2: jt = r + 8 (waves 0..4), inline loads ----
    if (r < NJT - 8) {
        const int jrow = (r + 8) * 16 + jcol;
        const int jl   = (jrow < NB) ? jrow : (NB - 1);
        f32x4 acc0 = {0.f, 0.f, 0.f, 0.f};
        f32x4 acc1 = {0.f, 0.f, 0.f, 0.f};
        const unsigned* bhp = hs_hi + ((size_t)(b * NB + jl) << 6) + kgrp * 4;
        const unsigned* blp = hs_lo + ((size_t)(b * NB + jl) << 6) + kgrp * 4;
        #pragma unroll
        for (int ks = 0; ks < 4; ++ks) {
            short8v Bh = __builtin_bit_cast(short8v, *(const u32x4*)(bhp + ks * 16));
            short8v Bl = __builtin_bit_cast(short8v, *(const u32x4*)(blp + ks * 16));
            acc0 = __builtin_amdgcn_mfma_f32_16x16x32_bf16(Ahi[0][ks], Bh, acc0, 0, 0, 0);
            acc0 = __builtin_amdgcn_mfma_f32_16x16x32_bf16(Ahi[0][ks], Bl, acc0, 0, 0, 0);
            acc1 = __builtin_amdgcn_mfma_f32_16x16x32_bf16(Ahi[1][ks], Bh, acc1, 0, 0, 0);
            acc1 = __builtin_amdgcn_mfma_f32_16x16x32_bf16(Ahi[1][ks], Bl, acc1, 0, 0, 0);
        }
        const int mm  = mask[b * NB + jl];
        const int kk0 = adj[(size_t)(b * NB + i0 + kgrp) * NB + jl];
        const int kk1 = adj[(size_t)(b * NB + i0 + 4 + kgrp) * NB + jl];
        float ev0 = (kk0 == 1) ? acc0[0] : (kk0 == 2) ? acc0[1] :
                    (kk0 == 3) ? acc0[2] : (kk0 == 4) ? acc0[3] : 0.0f;
        float ev1 = (kk1 == 1) ? acc1[0] : (kk1 == 2) ? acc1[1] :
                    (kk1 == 3) ? acc1[2] : (kk1 == 4) ? acc1[3] : 0.0f;
        ev0 = (ev0 >= 0.0f) ? ev0 : 0.2f * ev0;
        ev1 = (ev1 >= 0.0f) ? ev1 : 0.2f * ev1;
        float xv0 = ev0 * 0.1f;
        float xv1 = ev1 * 0.1f;
        if (mm == 0 || jrow >= NB) { xv0 = -INFINITY; xv1 = -INFINITY; }
        xs[kgrp][jrow]     = xv0;
        xs[4 + kgrp][jrow] = xv1;
    }
    __syncthreads();                                   // B

    // ==== PREFETCH 2: PV B-frags (ht) — retire during entmax's serial chain ====
    u32x4 pHt[7];
    {
        const int dc = 16 * r + (lane & 15);
        const size_t baseh = ((size_t)(b * DIMH + dc)) * KJ2 + (lane >> 4) * 4;
        #pragma unroll
        for (int ks = 0; ks < 7; ++ks)
            pHt[ks] = *(const u32x4*)(ht_hi + baseh + ks * 16);
    }

    // ---- entmax via Newton on ||(x-tau)+||_10 = 1 ----
    float x0 = xs[r][lane];
    float x1 = xs[r][lane + 64];
    float x2 = xs[r][lane + 128];
    float x3 = (lane < 16) ? xs[r][192 + lane] : -INFINITY;

    float mx  = wmax_dpp(fmaxf(fmaxf(x0, x1), fmaxf(x2, x3)));
    float tau = mx - 1.0f;
    #pragma unroll
    for (int itn = 0; itn < NNEWT; ++itn) {
        float t10 = 0.f, t9 = 0.f;
        #define ACC(xv) { float z_ = fmaxf((xv) - tau, 0.f); float e2 = z_*z_;   \
                          float e8 = e2*e2; e8 = e8*e8; float e9 = e8*z_;        \
                          t9 += e9; t10 = fmaf(e9, z_, t10); }
        ACC(x0) ACC(x1) ACC(x2) ACC(x3)
        #undef ACC
        wsum2_dpp(t10, t9);
        float u  = exp2f(0.1f * log2f(t10));
        tau += t10 * (1.0f - __builtin_amdgcn_rcpf(u)) * __builtin_amdgcn_rcpf(t9);
    }
    #define P10(v, tt) ({ float z_ = fmaxf((v) - (tt), 0.f); float z2 = z_*z_; float z4 = z2*z2; float z8 = z4*z4; z8*z2; })
    float p0 = P10(x0, tau);
    float p1 = P10(x1, tau);
    float p2 = P10(x2, tau);
    float p3 = P10(x3, tau);
    #undef P10
    float sinv = 1.0f / wsum_dpp(p0 + p1 + p2 + p3);   // ensure_sum_one
    xs[r][lane]       = p0 * sinv;
    xs[r][lane + 64]  = p1 * sinv;
    xs[r][lane + 128] = p2 * sinv;
    if (lane < 16) xs[r][192 + lane] = p3 * sinv;

    // ---- pbf row r built wave-locally ----
    for (int k2 = lane; k2 < KJ2; k2 += 64) {
        int j = 2 * k2;
        float v0 = (j < 208)     ? xs[r][j]     : 0.0f;
        float v1 = (j + 1 < 208) ? xs[r][j + 1] : 0.0f;
        pbf[r * 116 + k2]                = pack_hi2(v0, v1);
        pbf[ROWS8 * 116 + r * 116 + k2]  = pack_hi2(v0 - hi_of(v0), v1 - hi_of(v1));
    }
    __syncthreads();                                   // C

    // ==== PREFETCH 3: gate B-frags (wf) — retire during PV + barriers E/F ====
    u32x4 pWf[8];
    {
        #pragma unroll
        for (int ks = 0; ks < 8; ++ks)
            pWf[ks] = *(const u32x4*)&wf[((r * 8 + ks) * 64 + lane) * 4];
    }

    // ---- PV via MFMA: wave r does n-tile r; P hi/lo x H bf16 (B prefetched) ----
    {
        f32x4 av = {0.f, 0.f, 0.f, 0.f};
        const int prow = lane & 7;
        const int au   = (lane >> 4) * 4;
        #pragma unroll
        for (int ks = 0; ks < 7; ++ks) {
            short8v Ph = __builtin_bit_cast(short8v, *(const u32x4*)&pbf[prow * 116 + ks * 16 + au]);
            short8v Pl = __builtin_bit_cast(short8v, *(const u32x4*)&pbf[ROWS8 * 116 + prow * 116 + ks * 16 + au]);
            short8v Bh = __builtin_bit_cast(short8v, pHt[ks]);
            av = __builtin_amdgcn_mfma_f32_16x16x32_bf16(Ph, Bh, av, 0, 0, 0);
            av = __builtin_amdgcn_mfma_f32_16x16x32_bf16(Pl, Bh, av, 0, 0, 0);
        }
        if (lane < 32) {
            const int rbase = (lane >> 4) * 4;
            #pragma unroll
            for (int q = 0; q < 4; ++q)
                cop[rbase + q][DIMH + 16 * r + (lane & 15)] = av[q];
        }
    }
    __syncthreads();                                   // E (pbf dead after this)

    float2 ovv = *(const float2*)&cop[r][DIMH + d2];

    // ---- gate via MFMA: C hi/lo x W bf16 (B prefetched) ----
    {
        float hx = cop[r][d2], hy = cop[r][d2 + 1];
        CBF(0, r, lane)      = pack_hi2(hx, hy);
        CBF(1, r, lane)      = pack_hi2(hx - hi_of(hx), hy - hi_of(hy));
        CBF(0, r, 64 + lane) = pack_hi2(ovv.x, ovv.y);
        CBF(1, r, 64 + lane) = pack_hi2(ovv.x - hi_of(ovv.x), ovv.y - hi_of(ovv.y));
    }
    __syncthreads();                                   // F

    {
        f32x4 ga = {0.f, 0.f, 0.f, 0.f};
        const int arow = lane & 7;
        const int au   = (lane >> 4) * 4;
        #pragma unroll
        for (int ks = 0; ks < 8; ++ks) {
            short8v Ah = __builtin_bit_cast(short8v, *(const u32x4*)&CBF(0, arow, ks * 16 + au));
            short8v Al = __builtin_bit_cast(short8v, *(const u32x4*)&CBF(1, arow, ks * 16 + au));
            short8v Bh = __builtin_bit_cast(short8v, pWf[ks]);
            ga = __builtin_amdgcn_mfma_f32_16x16x32_bf16(Ah, Bh, ga, 0, 0, 0);
            ga = __builtin_amdgcn_mfma_f32_16x16x32_bf16(Al, Bh, ga, 0, 0, 0);
        }
        if (lane < 32) {
            const int rbase = (lane >> 4) * 4;
            #pragma unroll
            for (int q = 0; q < 4; ++q)
                xs[rbase + q][16 * r + (lane & 15)] = ga[q];
        }
    }
    __syncthreads();                                   // G

    // ---- final ----
    {
        float2 bv = *(const float2*)(bias + d2);
        float gx = xs[r][d2]     + bv.x;
        float gy = xs[r][d2 + 1] + bv.y;
        float sgx = 1.0f / (1.0f + __expf(-gx));
        float sgy = 1.0f / (1.0f + __expf(-gy));
        float2 hf = *(const float2*)&cop[r][d2];
        const size_t gi = (size_t)(b * NB + i0 + r) * DIMH;
        float2 res;
        res.x = sgx * ovv.x + (1.0f - sgx) * hf.x;
        res.y = sgy * ovv.y + (1.0f - sgy) * hf.y;
        *(float2*)(out + gi + d2) = res;
    }
    #undef CBF
}

// ========== fallback: no-ws 4-row f32 kernel (round-9 structure) ==========
#define ROWS  4
#define TPB   256
__global__ __launch_bounds__(TPB, 4) void la_basic(
    const float* __restrict__ hidden,
    const int*   __restrict__ adj,
    const int*   __restrict__ mask,
    const float* __restrict__ a0, const float* __restrict__ a1,
    const float* __restrict__ a2, const float* __restrict__ a3,
    const float* __restrict__ W,  const float* __restrict__ bias,
    float* __restrict__ out)
{
    __shared__ float ha[ROWS][4][132];
    __shared__ float xs[ROWS][208];
    __shared__ float cop[ROWS][256];
    __shared__ float scrf[ROWS * ROWS * DIMH];

    const int t    = threadIdx.x;
    const int lane = t & 63;
    const int r    = t >> 6;
    const int d2   = 2 * lane;
    const int bid  = blockIdx.x;
    const int b    = bid / (NB / ROWS);
    const int i0   = (bid % (NB / ROWS)) * ROWS;

    const float* hb = hidden + (size_t)b * NB * DIMH;

    for (int idx = t; idx < ROWS * DIMH; idx += TPB) {
        int rr = idx >> 7, d = idx & 127;
        cop[rr][d] = hb[(i0 + rr) * DIMH + d];
    }
    for (int idx = t; idx < ROWS * 4 * DIMH; idx += TPB) {
        int rr = idx >> 9, k = (idx >> 7) & 3, d = idx & 127;
        float av = (k == 0) ? a0[d] : (k == 1) ? a1[d] : (k == 2) ? a2[d] : a3[d];
        ha[rr][k][d] = hb[(i0 + rr) * DIMH + d] * av;
    }
    __syncthreads();

    if (t < NB) {
        const int m = mask[b * NB + t];
        int kk[ROWS];
        #pragma unroll
        for (int rr = 0; rr < ROWS; rr++)
            kk[rr] = adj[((size_t)(b * NB + i0 + rr)) * NB + t];
        int ksel[ROWS];
        #pragma unroll
        for (int rr = 0; rr < ROWS; rr++) ksel[rr] = (kk[rr] > 0) ? (kk[rr] - 1) : 0;
        float acc[ROWS] = {0.f, 0.f, 0.f, 0.f};
        const float* hj = hb + t * DIMH;
        #pragma unroll 4
        for (int d = 0; d < DIMH; d += 4) {
            float4 hv = *(const float4*)(hj + d);
            #pragma unroll
            for (int rr = 0; rr < ROWS; rr++) {
                const float4 av4 = *(const float4*)&ha[rr][ksel[rr]][d];
                acc[rr] = fmaf(hv.x, av4.x, acc[rr]);
                acc[rr] = fmaf(hv.y, av4.y, acc[rr]);
                acc[rr] = fmaf(hv.z, av4.z, acc[rr]);
                acc[rr] = fmaf(hv.w, av4.w, acc[rr]);
            }
        }
        #pragma unroll
        for (int rr = 0; rr < ROWS; rr++) {
            float x;
            if (m == 0)           x = -INFINITY;
            else if (kk[rr] == 0) x = 0.0f;
            else {
                float e = acc[rr];
                e = (e >= 0.0f) ? e : 0.2f * e;
                x = e * 0.1f;
            }
            xs[rr][t] = x;
        }
    } else if (t < 208) {
        #pragma unroll
        for (int rr = 0; rr < ROWS; rr++) xs[rr][t] = -INFINITY;
    }
    __syncthreads();

    float x0 = xs[r][lane];
    float x1 = xs[r][lane + 64];
    float x2 = xs[r][lane + 128];
    float x3 = (lane < 16) ? xs[r][192 + lane] : -INFINITY;

    float mx  = wmax_dpp(fmaxf(fmaxf(x0, x1), fmaxf(x2, x3)));
    float tau = mx - 1.0f;
    #define P10(v, tt) ({ float z_ = fmaxf((v) - (tt), 0.f); float z2 = z_*z_; float z4 = z2*z2; float z8 = z4*z4; z8*z2; })
    float s0 = P10(x0, tau) + P10(x1, tau) + P10(x2, tau) + P10(x3, tau);
    float f_lo = wsum_dpp(s0) - 1.0f;
    float dm   = (mx - 0.58870401f) - tau;
    for (int itn = 0; itn < NITER; ++itn) {
        dm *= 0.5f;
        float tm = tau + dm;
        float s = P10(x0, tm) + P10(x1, tm) + P10(x2, tm) + P10(x3, tm);
        float fm = wsum_dpp(s) - 1.0f;
        if (fm * f_lo >= 0.0f) tau = tm;
    }
    float p0 = P10(x0, tau);
    float p1 = P10(x1, tau);
    float p2 = P10(x2, tau);
    float p3 = P10(x3, tau);
    #undef P10
    float sinv = 1.0f / wsum_dpp(p0 + p1 + p2 + p3);
    xs[r][lane]       = p0 * sinv;
    xs[r][lane + 64]  = p1 * sinv;
    xs[r][lane + 128] = p2 * sinv;
    if (lane < 16) xs[r][192 + lane] = p3 * sinv;
    __syncthreads();

    const int J0 = r * 50;
    float pj0 = (lane < 50) ? xs[0][J0 + lane] : 0.f;
    float pj1 = (lane < 50) ? xs[1][J0 + lane] : 0.f;
    float pj2 = (lane < 50) ? xs[2][J0 + lane] : 0.f;
    float pj3 = (lane < 50) ? xs[3][J0 + lane] : 0.f;
    float2 ov0 = {0.f,0.f}, ov1 = {0.f,0.f}, ov2 = {0.f,0.f}, ov3 = {0.f,0.f};
    {
        const float* hjb = hb + (size_t)J0 * DIMH + d2;
        #pragma unroll 5
        for (int jj = 0; jj < 50; ++jj) {
            float2 hv = *(const float2*)(hjb + jj * DIMH);
            float c0 = rdlane(pj0, jj), c1 = rdlane(pj1, jj);
            float c2 = rdlane(pj2, jj), c3 = rdlane(pj3, jj);
            ov0.x = fmaf(c0, hv.x, ov0.x); ov0.y = fmaf(c0, hv.y, ov0.y);
            ov1.x = fmaf(c1, hv.x, ov1.x); ov1.y = fmaf(c1, hv.y, ov1.y);
            ov2.x = fmaf(c2, hv.x, ov2.x); ov2.y = fmaf(c2, hv.y, ov2.y);
            ov3.x = fmaf(c3, hv.x, ov3.x); ov3.y = fmaf(c3, hv.y, ov3.y);
        }
    }
    *(float2*)&scrf[(r * 4 + 0) * DIMH + d2] = ov0;
    *(float2*)&scrf[(r * 4 + 1) * DIMH + d2] = ov1;
    *(float2*)&scrf[(r * 4 + 2) * DIMH + d2] = ov2;
    *(float2*)&scrf[(r * 4 + 3) * DIMH + d2] = ov3;
    __syncthreads();
    float2 o;
    {
        float2 q0 = *(const float2*)&scrf[(0 * 4 + r) * DIMH + d2];
        float2 q1 = *(const float2*)&scrf[(1 * 4 + r) * DIMH + d2];
        float2 q2 = *(const float2*)&scrf[(2 * 4 + r) * DIMH + d2];
        float2 q3 = *(const float2*)&scrf[(3 * 4 + r) * DIMH + d2];
        o.x = (q0.x + q1.x) + (q2.x + q3.x);
        o.y = (q0.y + q1.y) + (q2.y + q3.y);
    }
    *(float2*)&cop[r][DIMH + d2] = o;
    __syncthreads();

    float2 ov = *(const float2*)&cop[r][DIMH + d2];
    float cv0 = cop[0][64 * r + lane];
    float cv1 = cop[1][64 * r + lane];
    float cv2 = cop[2][64 * r + lane];
    float cv3 = cop[3][64 * r + lane];
    float2 gv0 = {0.f,0.f}, gv1 = {0.f,0.f}, gv2 = {0.f,0.f}, gv3 = {0.f,0.f};
    {
        const float* wb = W + (size_t)(64 * r) * DIMH + d2;
        #pragma unroll 8
        for (int ee = 0; ee < 64; ++ee) {
            float2 wv = *(const float2*)(wb + ee * DIMH);
            float c0 = rdlane(cv0, ee), c1 = rdlane(cv1, ee);
            float c2 = rdlane(cv2, ee), c3 = rdlane(cv3, ee);
            gv0.x = fmaf(c0, wv.x, gv0.x); gv0.y = fmaf(c0, wv.y, gv0.y);
            gv1.x = fmaf(c1, wv.x, gv1.x); gv1.y = fmaf(c1, wv.y, gv1.y);
            gv2.x = fmaf(c2, wv.x, gv2.x); gv2.y = fmaf(c2, wv.y, gv2.y);
            gv3.x = fmaf(c3, wv.x, gv3.x); gv3.y = fmaf(c3, wv.y, gv3.y);
        }
    }
    *(float2*)&scrf[(r * 4 + 0) * DIMH + d2] = gv0;
    *(float2*)&scrf[(r * 4 + 1) * DIMH + d2] = gv1;
    *(float2*)&scrf[(r * 4 + 2) * DIMH + d2] = gv2;
    *(float2*)&scrf[(r * 4 + 3) * DIMH + d2] = gv3;
    __syncthreads();
    {
        float2 q0 = *(const float2*)&scrf[(0 * 4 + r) * DIMH + d2];
        float2 q1 = *(const float2*)&scrf[(1 * 4 + r) * DIMH + d2];
        float2 q2 = *(const float2*)&scrf[(2 * 4 + r) * DIMH + d2];
        float2 q3 = *(const float2*)&scrf[(3 * 4 + r) * DIMH + d2];
        float2 bv = *(const float2*)(bias + d2);
        float gx = ((q0.x + q1.x) + (q2.x + q3.x)) + bv.x;
        float gy = ((q0.y + q1.y) + (q2.y + q3.y)) + bv.y;
        float sgx = 1.0f / (1.0f + __expf(-gx));
        float sgy = 1.0f / (1.0f + __expf(-gy));
        float2 hf = *(const float2*)&cop[r][d2];
        const size_t gi = (size_t)(b * NB + i0 + r) * DIMH;
        float2 res;
        res.x = sgx * ov.x + (1.0f - sgx) * hf.x;
        res.y = sgy * ov.y + (1.0f - sgy) * hf.y;
        *(float2*)(out + gi + d2) = res;
    }
}

extern "C" void kernel_launch(void* const* d_in, const int* in_sizes, int n_in,
                              void* d_out, int out_size, void* d_ws, size_t ws_size,
                              hipStream_t stream)
{
    const float* hidden = (const float*)d_in[0];
    const int*   adj    = (const int*)d_in[1];
    const int*   mask   = (const int*)d_in[2];
    const float* a0     = (const float*)d_in[3];
    const float* a1     = (const float*)d_in[4];
    const float* a2     = (const float*)d_in[5];
    const float* a3     = (const float*)d_in[6];
    const float* W      = (const float*)d_in[7];
    const float* bias   = (const float*)d_in[8];
    float* out = (float*)d_out;

    const int B = in_sizes[0] / (NB * DIMH);   // 256
    const int NBLK = B * (NB / ROWS8);         // 6400

    const size_t hsN = (size_t)B * NB * 64;
    const size_t htN = (size_t)B * DIMH * KJ2;
    const size_t tblU32 = (size_t)WF_U32 + 2 * hsN + 2 * htN;  // ht_lo slot reserved

    if (ws_size >= tblU32 * sizeof(unsigned)) {
        unsigned* wf    = (unsigned*)d_ws;
        unsigned* hs_hi = wf + WF_U32;
        unsigned* hs_lo = hs_hi + hsN;
        unsigned* ht_hi = hs_lo + hsN;
        conv_w<<<64, 64, 0, stream>>>(W, wf);
        conv_hs<<<(unsigned)(hsN / 256), 256, 0, stream>>>(hidden, hs_hi, hs_lo);
        conv_ht<<<B * 28, 256, 0, stream>>>(hidden, ht_hi);
        la_fused8<<<NBLK, TPB8, 0, stream>>>(hidden, adj, mask, a0, a1, a2, a3,
                                             bias, wf, hs_hi, hs_lo, ht_hi, out);
    } else {
        la_basic<<<B * (NB / ROWS), TPB, 0, stream>>>(hidden, adj, mask,
                                                      a0, a1, a2, a3, W, bias, out);
    }
}